// Round 12
// baseline (827.363 us; speedup 1.0000x reference)
//
#include <hip/hip_runtime.h>
#include <math.h>

#define NN 50000
#define NE 600000
#define NG 1000
#define HC 32
#define NSCB ((NN + 255) / 256)   // 196 scan blocks

__device__ __forceinline__ float softplusf(float s) {
    return fmaxf(s, 0.f) + log1pf(expf(-fabsf(s)));
}

__device__ __forceinline__ float4 shflx4(float4 v, int m) {
    v.x = __shfl_xor(v.x, m, 32);
    v.y = __shfl_xor(v.y, m, 32);
    v.z = __shfl_xor(v.z, m, 32);
    v.w = __shfl_xor(v.w, m, 32);
    return v;
}

__device__ __forceinline__ float dot4(float4 a, float4 b) {
    return a.x * b.x + a.y * b.y + a.z * b.z + a.w * b.w;
}

// ---------------- setup kernels ----------------

__global__ __launch_bounds__(256) void k_deg(const int* __restrict__ dst, int* __restrict__ deg) {
    int e = blockIdx.x * 256 + threadIdx.x;
    if (e < NE) atomicAdd(&deg[dst[e]], 1);
}

__global__ __launch_bounds__(256) void k_scan1(const int* __restrict__ deg, int* __restrict__ bscan) {
    __shared__ int sm[256];
    int t = threadIdx.x;
    int i = blockIdx.x * 256 + t;
    sm[t] = (i < NN) ? deg[i] : 0;
    __syncthreads();
    for (int o = 128; o > 0; o >>= 1) {
        if (t < o) sm[t] += sm[t + o];
        __syncthreads();
    }
    if (t == 0) bscan[blockIdx.x] = sm[0];
}

__global__ __launch_bounds__(256) void k_scan2(int* __restrict__ bscan) {
    __shared__ int sm[256];
    int t = threadIdx.x;
    int v = (t < NSCB) ? bscan[t] : 0;
    sm[t] = v;
    __syncthreads();
    for (int o = 1; o < 256; o <<= 1) {
        int u = (t >= o) ? sm[t - o] : 0;
        __syncthreads();
        sm[t] += u;
        __syncthreads();
    }
    if (t < NSCB) bscan[t] = sm[t] - v;  // exclusive
}

__global__ __launch_bounds__(256) void k_scan3(const int* __restrict__ deg, const int* __restrict__ bscan,
                                               int* __restrict__ rowstart, float* __restrict__ dinv) {
    __shared__ int sm[256];
    int t = threadIdx.x;
    int i = blockIdx.x * 256 + t;
    int d = (i < NN) ? deg[i] : 0;
    sm[t] = d;
    __syncthreads();
    for (int o = 1; o < 256; o <<= 1) {
        int u = (t >= o) ? sm[t - o] : 0;
        __syncthreads();
        sm[t] += u;
        __syncthreads();
    }
    int incl = sm[t];
    if (i < NN) {
        rowstart[i] = bscan[blockIdx.x] + incl - d;
        dinv[i] = d > 0 ? rsqrtf((float)d) : 0.f;
    }
    if (i == NN - 1) rowstart[NN] = bscan[blockIdx.x] + incl;
}

__global__ __launch_bounds__(256) void k_csr(const int* __restrict__ src, const int* __restrict__ dst,
                                             const int* __restrict__ rowstart, int* __restrict__ cursor,
                                             int* __restrict__ csr_src) {
    int e = blockIdx.x * 256 + threadIdx.x;
    if (e < NE) {
        int d = dst[e];
        int p = atomicAdd(&cursor[d], 1);
        csr_src[rowstart[d] + p] = src[e];
    }
}

// ---------------- AtomEncoder + first conv1 transform ----------------
__global__ __launch_bounds__(256) void k_atom_mm(const int* __restrict__ x, const float* __restrict__ emb,
                                                 const float* __restrict__ W, float* __restrict__ h,
                                                 float* __restrict__ hw) {
    __shared__ float wl[HC * HC];
    __shared__ float il[8][HC];
    int t = threadIdx.x;
    ((float4*)wl)[t] = ((const float4*)W)[t];
    int slot = t >> 5, c = t & 31;
    int n = blockIdx.x * 8 + slot;
    float s = 0.f;
#pragma unroll
    for (int j = 0; j < 9; j++) {
        int v = x[n * 9 + j];
        s += emb[(j * 100 + v) * HC + c];
    }
    __syncthreads();   // staging barrier (weights)
    h[n * HC + c] = s;
    il[slot][c] = s;   // intra-wave sharing only below
    float o = 0.f;
#pragma unroll
    for (int k = 0; k < HC; k++) o += il[slot][k] * wl[k * HC + c];
    hw[n * HC + c] = o;
}

// ---------------- aggregation only: no LDS, no barrier, low VGPR ----------------
template <int AGGR>
__global__ __launch_bounds__(256) void k_agg(const float* __restrict__ hw,
                                             const int* __restrict__ rowstart, const int* __restrict__ csr_src,
                                             float* __restrict__ aout) {
    int t = threadIdx.x;
    int slot = t >> 5, c = t & 31;
    int sub = c >> 3;
    int ch4 = (c & 7) * 4;
    int n = blockIdx.x * 8 + slot;
    int rs = rowstart[n], re = rowstart[n + 1];
    float4 a4;
    if (AGGR == 0) {
        float4 m4 = make_float4(3.0e38f, 3.0e38f, 3.0e38f, 3.0e38f);
        for (int base = rs; base < re; base += 32) {
            int cnt = min(re - base, 32);
            int myidx = (c < cnt) ? csr_src[base + c] : 0;
#pragma unroll
            for (int jj = 0; jj < 8; jj++) {
                int r = jj * 4 + sub;
                int sidx = __shfl(myidx, r, 32);
                if (r < cnt) {
                    float4 v = *(const float4*)(hw + sidx * HC + ch4);
                    m4.x = fminf(m4.x, v.x); m4.y = fminf(m4.y, v.y);
                    m4.z = fminf(m4.z, v.z); m4.w = fminf(m4.w, v.w);
                }
            }
        }
        float4 o4 = shflx4(m4, 8);
        m4.x = fminf(m4.x, o4.x); m4.y = fminf(m4.y, o4.y); m4.z = fminf(m4.z, o4.z); m4.w = fminf(m4.w, o4.w);
        o4 = shflx4(m4, 16);
        m4.x = fminf(m4.x, o4.x); m4.y = fminf(m4.y, o4.y); m4.z = fminf(m4.z, o4.z); m4.w = fminf(m4.w, o4.w);
        a4 = (re > rs) ? m4 : make_float4(0.f, 0.f, 0.f, 0.f);
    } else {
        float4 lg = make_float4(0.f, 0.f, 0.f, 0.f);
        int4 ng = make_int4(0, 0, 0, 0);
        for (int base = rs; base < re; base += 32) {
            int cnt = min(re - base, 32);
            int myidx = (c < cnt) ? csr_src[base + c] : 0;
#pragma unroll
            for (int jj = 0; jj < 8; jj++) {
                int r = jj * 4 + sub;
                int sidx = __shfl(myidx, r, 32);
                if (r < cnt) {
                    float4 v = *(const float4*)(hw + sidx * HC + ch4);
                    ng.x += (v.x < 0.f) ? 1 : 0; ng.y += (v.y < 0.f) ? 1 : 0;
                    ng.z += (v.z < 0.f) ? 1 : 0; ng.w += (v.w < 0.f) ? 1 : 0;
                    lg.x += __logf(fabsf(v.x)); lg.y += __logf(fabsf(v.y));
                    lg.z += __logf(fabsf(v.z)); lg.w += __logf(fabsf(v.w));
                }
            }
        }
        float4 o4 = shflx4(lg, 8);
        lg.x += o4.x; lg.y += o4.y; lg.z += o4.z; lg.w += o4.w;
        o4 = shflx4(lg, 16);
        lg.x += o4.x; lg.y += o4.y; lg.z += o4.z; lg.w += o4.w;
        ng.x += __shfl_xor(ng.x, 8, 32); ng.y += __shfl_xor(ng.y, 8, 32);
        ng.z += __shfl_xor(ng.z, 8, 32); ng.w += __shfl_xor(ng.w, 8, 32);
        ng.x += __shfl_xor(ng.x, 16, 32); ng.y += __shfl_xor(ng.y, 16, 32);
        ng.z += __shfl_xor(ng.z, 16, 32); ng.w += __shfl_xor(ng.w, 16, 32);
        if (re > rs) {
            float ex = __expf(lg.x); a4.x = (ng.x & 1) ? -ex : ex;
            ex = __expf(lg.y); a4.y = (ng.y & 1) ? -ex : ex;
            ex = __expf(lg.z); a4.z = (ng.z & 1) ? -ex : ex;
            ex = __expf(lg.w); a4.w = (ng.w & 1) ? -ex : ex;
        } else {
            a4 = make_float4(0.f, 0.f, 0.f, 0.f);
        }
    }
    if (c < 8) *(float4*)(aout + n * HC + ch4) = a4;
}

// ---------------- GRU update v4: 8 nodes/thread, b128 LDS, capped unroll ----------------
// 256 threads = 8 slots x 32 channels; block covers 64 nodes. Weights row-contiguous in LDS,
// stride 36 dwords. unroll 1 on k4 loop keeps VGPR < 128 (R10 lesson). EPI: 0 none, 1 h@Wn,
// 2 relu(h@Wn + nb).
#define WS 36   // dword stride for weight rows (9 float4)
template <bool POSTRELU, int EPI>
__global__ __launch_bounds__(256) void k_gru(const float* __restrict__ aIn, float* __restrict__ h,
                                             const float* __restrict__ wih, const float* __restrict__ whh,
                                             const float* __restrict__ bih, const float* __restrict__ bhh,
                                             const float* __restrict__ Wn, const float* __restrict__ nb,
                                             float* __restrict__ out_next) {
    __shared__ float wiL[96 * WS];
    __shared__ float whL[96 * WS];
    __shared__ float wnT[EPI > 0 ? 32 * WS : 4];
    __shared__ float al[64][HC];
    __shared__ float hl[64][HC];
    int t = threadIdx.x;
    // stage wi/wh row-contiguous (768 float4 each)
    for (int i4 = t; i4 < 768; i4 += 256) {
        int row = i4 >> 3, k4 = i4 & 7;
        ((float4*)wiL)[row * 9 + k4] = ((const float4*)wih)[i4];
        ((float4*)whL)[row * 9 + k4] = ((const float4*)whh)[i4];
    }
    if (EPI > 0) {
        // transpose Wn[k][c] -> wnT[c][k] (stride WS)
        int i = t * 4;
        int k = i >> 5, c0 = i & 31;
        float4 v = ((const float4*)Wn)[t];
        wnT[(c0 + 0) * WS + k] = v.x;
        wnT[(c0 + 1) * WS + k] = v.y;
        wnT[(c0 + 2) * WS + k] = v.z;
        wnT[(c0 + 3) * WS + k] = v.w;
    }
    int slot = t >> 5, c = t & 31;
    int nb0 = blockIdx.x * 64 + slot * 8;
    float b_ir = bih[c], b_iz = bih[HC + c], b_in = bih[2 * HC + c];
    float b_hr = bhh[c], b_hz = bhh[HC + c], b_hn = bhh[2 * HC + c];
    float nbv = (EPI == 2) ? nb[c] : 0.f;
    float hv[8];
#pragma unroll
    for (int j = 0; j < 8; j++) {
        int n = nb0 + j;
        float aa = 0.f, hh = 0.f;
        if (n < NN) {
            aa = aIn[n * HC + c];
            hh = h[n * HC + c];
        }
        hv[j] = hh;
        al[slot * 8 + j][c] = aa;
        hl[slot * 8 + j][c] = hh;
    }
    __syncthreads();   // single barrier: weights staged

    float aIR[8], aIZ[8], aIN[8], aHR[8], aHZ[8], aHN[8];
#pragma unroll
    for (int j = 0; j < 8; j++) {
        aIR[j] = b_ir; aIZ[j] = b_iz; aIN[j] = b_in;
        aHR[j] = b_hr; aHZ[j] = b_hz; aHN[j] = b_hn;
    }
    const float4* wi4 = (const float4*)wiL;
    const float4* wh4 = (const float4*)whL;
    int r0 = c * 9, r1 = (32 + c) * 9, r2 = (64 + c) * 9;
#pragma unroll 1
    for (int k4 = 0; k4 < 8; k4++) {
        float4 wir = wi4[r0 + k4], wiz = wi4[r1 + k4], win = wi4[r2 + k4];
        float4 whr = wh4[r0 + k4], whz = wh4[r1 + k4], whn = wh4[r2 + k4];
#pragma unroll
        for (int j = 0; j < 8; j++) {
            float4 av = *(const float4*)&al[slot * 8 + j][k4 * 4];
            float4 hb = *(const float4*)&hl[slot * 8 + j][k4 * 4];
            aIR[j] += dot4(av, wir);
            aIZ[j] += dot4(av, wiz);
            aIN[j] += dot4(av, win);
            aHR[j] += dot4(hb, whr);
            aHZ[j] += dot4(hb, whz);
            aHN[j] += dot4(hb, whn);
        }
    }
    float hn[8];
#pragma unroll
    for (int j = 0; j < 8; j++) {
        float r = 1.f / (1.f + __expf(-(aIR[j] + aHR[j])));
        float z = 1.f / (1.f + __expf(-(aIZ[j] + aHZ[j])));
        float nnv = tanhf(aIN[j] + r * aHN[j]);
        float v = (1.f - z) * nnv + z * hv[j];
        if (POSTRELU) v = fmaxf(v, 0.f);
        hn[j] = v;
        int n = nb0 + j;
        if (n < NN) h[n * HC + c] = v;
    }
    if (EPI > 0) {
        // reuse al for h_new (intra-half-wave, lockstep -> no barrier)
#pragma unroll
        for (int j = 0; j < 8; j++) al[slot * 8 + j][c] = hn[j];
        float accE[8];
#pragma unroll
        for (int j = 0; j < 8; j++) accE[j] = (EPI == 2) ? nbv : 0.f;
        const float4* wn4 = (const float4*)wnT;
        int rc = c * 9;
#pragma unroll 1
        for (int k4 = 0; k4 < 8; k4++) {
            float4 wv = wn4[rc + k4];
#pragma unroll
            for (int j = 0; j < 8; j++) {
                float4 hb = *(const float4*)&al[slot * 8 + j][k4 * 4];
                accE[j] += dot4(hb, wv);
            }
        }
#pragma unroll
        for (int j = 0; j < 8; j++) {
            float o = accE[j];
            if (EPI == 2) o = fmaxf(o, 0.f);
            int n = nb0 + j;
            if (n < NN) out_next[n * HC + c] = o;
        }
    }
}

// ---------------- conv2: GraphConv sum + two matmuls + ELU + fused bn2 partial reduction ----------------
__global__ __launch_bounds__(256) void k_conv2(const float* __restrict__ h, float* __restrict__ out,
                                               const int* __restrict__ rowstart, const int* __restrict__ csr_src,
                                               const float* __restrict__ rel_w, const float* __restrict__ rel_b,
                                               const float* __restrict__ root_w, float* __restrict__ bnacc) {
    __shared__ float rw[HC * HC], ow[HC * HC];
    __shared__ float sl[8][HC], hl[8][HC];
    int t = threadIdx.x;
    ((float4*)rw)[t] = ((const float4*)rel_w)[t];
    ((float4*)ow)[t] = ((const float4*)root_w)[t];
    int slot = t >> 5, c = t & 31;
    int sub = c >> 3;
    int ch4 = (c & 7) * 4;
    int n = blockIdx.x * 8 + slot;
    int rs = rowstart[n], re = rowstart[n + 1];
    __syncthreads();   // staging barrier
    float4 s4 = make_float4(0.f, 0.f, 0.f, 0.f);
    for (int base = rs; base < re; base += 32) {
        int cnt = min(re - base, 32);
        int myidx = (c < cnt) ? csr_src[base + c] : 0;
#pragma unroll
        for (int jj = 0; jj < 8; jj++) {
            int r = jj * 4 + sub;
            int sidx = __shfl(myidx, r, 32);
            if (r < cnt) {
                float4 v = *(const float4*)(h + sidx * HC + ch4);
                s4.x += v.x; s4.y += v.y; s4.z += v.z; s4.w += v.w;
            }
        }
    }
    float4 o4 = shflx4(s4, 8);
    s4.x += o4.x; s4.y += o4.y; s4.z += o4.z; s4.w += o4.w;
    o4 = shflx4(s4, 16);
    s4.x += o4.x; s4.y += o4.y; s4.z += o4.z; s4.w += o4.w;
    if (c < 8) *(float4*)&sl[slot][ch4] = s4;
    float hv = h[n * HC + c];
    hl[slot][c] = hv;
    float o = rel_b[c];
#pragma unroll
    for (int k = 0; k < HC; k++) o += sl[slot][k] * rw[k * HC + c] + hl[slot][k] * ow[k * HC + c];
    o = (o > 0.f) ? o : expm1f(o);
    out[n * HC + c] = o;
    // fused bn2 partial reduction (cross-slot: barrier then slot 0 accumulates)
    __syncthreads();
    sl[slot][c] = o;
    hl[slot][c] = o * o;
    __syncthreads();
    if (slot == 0) {
        float s = 0.f, q = 0.f;
        for (int i = 0; i < 8; i++) {
            s += sl[i][c];
            q += hl[i][c];
        }
        atomicAdd(&bnacc[c], s);
        atomicAdd(&bnacc[HC + c], q);
    }
}

// ---------------- bn2 apply (in place) + first conv3 transform ----------------
__global__ __launch_bounds__(256) void k_bnapply_mm(float* __restrict__ h, const float* __restrict__ acc,
                                                    const float* __restrict__ g_, const float* __restrict__ b,
                                                    const float* __restrict__ W, float* __restrict__ out) {
    __shared__ float wl[HC * HC];
    __shared__ float il[8][HC];
    int t = threadIdx.x;
    ((float4*)wl)[t] = ((const float4*)W)[t];
    int slot = t >> 5, c = t & 31;
    int n = blockIdx.x * 8 + slot;
    float mu = acc[c] * (1.f / NN);
    float var = acc[HC + c] * (1.f / NN) - mu * mu;
    float v = (h[n * HC + c] - mu) * rsqrtf(var + 1e-5f) * g_[c] + b[c];
    __syncthreads();   // staging barrier
    h[n * HC + c] = v;
    il[slot][c] = v;
    float s = 0.f;
#pragma unroll
    for (int k = 0; k < HC; k++) s += il[slot][k] * wl[k * HC + c];
    out[n * HC + c] = s;
}

// ---------------- conv4 initial: acc = h@W0, S = dinv*h ----------------
__global__ __launch_bounds__(256) void k_mm_tag(const float* __restrict__ in, const float* __restrict__ W,
                                                float* __restrict__ acc, float* __restrict__ S,
                                                const float* __restrict__ dinv) {
    __shared__ float wl[HC * HC];
    __shared__ float il[8][HC];
    int t = threadIdx.x;
    ((float4*)wl)[t] = ((const float4*)W)[t];
    int slot = t >> 5, c = t & 31;
    int n = blockIdx.x * 8 + slot;
    float v = in[n * HC + c];
    __syncthreads();   // staging barrier
    il[slot][c] = v;
    S[n * HC + c] = dinv[n] * v;
    float s = 0.f;
#pragma unroll
    for (int k = 0; k < HC; k++) s += il[slot][k] * wl[k * HC + c];
    acc[n * HC + c] = s;
}

// ---------------- TAG hop on pre-scaled S; LAST fuses b4 + softplus(lin4) ----------------
template <bool LAST>
__global__ __launch_bounds__(256) void k_tag(const float* __restrict__ S, float* __restrict__ Snew,
                                             float* __restrict__ acc, const float* __restrict__ Wk,
                                             const int* __restrict__ rowstart, const int* __restrict__ csr_src,
                                             const float* __restrict__ dinv,
                                             const float* __restrict__ b4, const float* __restrict__ l4w,
                                             const float* __restrict__ l4b, float* __restrict__ out) {
    __shared__ float wl[HC * HC];
    __shared__ float w2[LAST ? HC * HC : 1];
    __shared__ float cl[8][HC];
    int t = threadIdx.x;
    ((float4*)wl)[t] = ((const float4*)Wk)[t];
    if (LAST) ((float4*)w2)[t] = ((const float4*)l4w)[t];
    int slot = t >> 5, c = t & 31;
    int sub = c >> 3;
    int ch4 = (c & 7) * 4;
    int n = blockIdx.x * 8 + slot;
    int rs = rowstart[n], re = rowstart[n + 1];
    __syncthreads();   // staging barrier
    float4 s4 = make_float4(0.f, 0.f, 0.f, 0.f);
    for (int base = rs; base < re; base += 32) {
        int cnt = min(re - base, 32);
        int myidx = (c < cnt) ? csr_src[base + c] : 0;
#pragma unroll
        for (int jj = 0; jj < 8; jj++) {
            int r = jj * 4 + sub;
            int sidx = __shfl(myidx, r, 32);
            if (r < cnt) {
                float4 v = *(const float4*)(S + sidx * HC + ch4);
                s4.x += v.x; s4.y += v.y; s4.z += v.z; s4.w += v.w;
            }
        }
    }
    float4 o4 = shflx4(s4, 8);
    s4.x += o4.x; s4.y += o4.y; s4.z += o4.z; s4.w += o4.w;
    o4 = shflx4(s4, 16);
    s4.x += o4.x; s4.y += o4.y; s4.z += o4.z; s4.w += o4.w;
    float di = dinv[n];
    if (c < 8) {
        float4 cn4 = make_float4(di * s4.x, di * s4.y, di * s4.z, di * s4.w);
        *(float4*)&cl[slot][ch4] = cn4;
        if (!LAST) {
            float4 sn4 = make_float4(di * cn4.x, di * cn4.y, di * cn4.z, di * cn4.w);
            *(float4*)(Snew + n * HC + ch4) = sn4;
        }
    }
    float o = 0.f;
#pragma unroll
    for (int k = 0; k < HC; k++) o += cl[slot][k] * wl[k * HC + c];
    if (!LAST) {
        acc[n * HC + c] += o;
    } else {
        float tmp = acc[n * HC + c] + o + b4[c];
        cl[slot][c] = tmp;   // intra-wave
        float o2 = l4b[c];
#pragma unroll
        for (int k = 0; k < HC; k++) o2 += cl[slot][k] * w2[k * HC + c];
        out[n * HC + c] = softplusf(o2);
    }
}

// ---------------- conv5: SAGE var-aggr + fused softplus(lin5) ----------------
__global__ __launch_bounds__(256) void k_sage(const float* __restrict__ h, float* __restrict__ out,
                                              const int* __restrict__ rowstart, const int* __restrict__ csr_src,
                                              const float* __restrict__ lw, const float* __restrict__ lb,
                                              const float* __restrict__ rw_, const float* __restrict__ l5w,
                                              const float* __restrict__ l5b) {
    __shared__ float wl[HC * HC], wr[HC * HC], w5[HC * HC];
    __shared__ float vl[8][HC], hl[8][HC];
    int t = threadIdx.x;
    ((float4*)wl)[t] = ((const float4*)lw)[t];
    ((float4*)wr)[t] = ((const float4*)rw_)[t];
    ((float4*)w5)[t] = ((const float4*)l5w)[t];
    int slot = t >> 5, c = t & 31;
    int sub = c >> 3;
    int ch4 = (c & 7) * 4;
    int n = blockIdx.x * 8 + slot;
    int rs = rowstart[n], re = rowstart[n + 1];
    __syncthreads();   // staging barrier
    float4 s4 = make_float4(0.f, 0.f, 0.f, 0.f);
    float4 q4 = make_float4(0.f, 0.f, 0.f, 0.f);
    for (int base = rs; base < re; base += 32) {
        int cnt = min(re - base, 32);
        int myidx = (c < cnt) ? csr_src[base + c] : 0;
#pragma unroll
        for (int jj = 0; jj < 8; jj++) {
            int r = jj * 4 + sub;
            int sidx = __shfl(myidx, r, 32);
            if (r < cnt) {
                float4 v = *(const float4*)(h + sidx * HC + ch4);
                s4.x += v.x; s4.y += v.y; s4.z += v.z; s4.w += v.w;
                q4.x += v.x * v.x; q4.y += v.y * v.y; q4.z += v.z * v.z; q4.w += v.w * v.w;
            }
        }
    }
    float4 o4 = shflx4(s4, 8);
    s4.x += o4.x; s4.y += o4.y; s4.z += o4.z; s4.w += o4.w;
    o4 = shflx4(s4, 16);
    s4.x += o4.x; s4.y += o4.y; s4.z += o4.z; s4.w += o4.w;
    o4 = shflx4(q4, 8);
    q4.x += o4.x; q4.y += o4.y; q4.z += o4.z; q4.w += o4.w;
    o4 = shflx4(q4, 16);
    q4.x += o4.x; q4.y += o4.y; q4.z += o4.z; q4.w += o4.w;
    float dc = fmaxf((float)(re - rs), 1.f);
    float inv = 1.f / dc;
    if (c < 8) {
        float4 var4;
        float m0 = s4.x * inv, m1 = s4.y * inv, m2 = s4.z * inv, m3 = s4.w * inv;
        var4.x = q4.x * inv - m0 * m0;
        var4.y = q4.y * inv - m1 * m1;
        var4.z = q4.z * inv - m2 * m2;
        var4.w = q4.w * inv - m3 * m3;
        *(float4*)&vl[slot][ch4] = var4;
    }
    float hv = h[n * HC + c];
    hl[slot][c] = hv;
    float o = lb[c];
#pragma unroll
    for (int k = 0; k < HC; k++) o += vl[slot][k] * wl[k * HC + c] + hl[slot][k] * wr[k * HC + c];
    vl[slot][c] = o;   // intra-wave
    float o2 = l5b[c];
#pragma unroll
    for (int k = 0; k < HC; k++) o2 += vl[slot][k] * w5[k * HC + c];
    out[n * HC + c] = softplusf(o2);
}

// ---------------- per-graph InstanceNorm + global max pool + final linear ----------------
__global__ __launch_bounds__(256) void k_final(const float* __restrict__ h, const int* __restrict__ batch,
                                               const float* __restrict__ linw, const float* __restrict__ linb,
                                               float* __restrict__ out) {
    __shared__ float r1[8][HC];
    __shared__ float r2[8][HC];
    __shared__ float gmv[HC], grs[HC], pooled[HC];
    int g = blockIdx.x;
    int t = threadIdx.x, slot = t >> 5, c = t & 31;
    int lo = 0, hi = NN;
    while (lo < hi) {
        int mid = (lo + hi) >> 1;
        if (batch[mid] < g) lo = mid + 1;
        else hi = mid;
    }
    int start = lo;
    hi = NN;
    while (lo < hi) {
        int mid = (lo + hi) >> 1;
        if (batch[mid] <= g) lo = mid + 1;
        else hi = mid;
    }
    int end = lo;
    int cnt = end - start;
    float s = 0.f, q = 0.f;
    for (int n = start + slot; n < end; n += 8) {
        float v = h[n * HC + c];
        s += v;
        q += v * v;
    }
    r1[slot][c] = s;
    r2[slot][c] = q;
    __syncthreads();
    if (slot == 0) {
        for (int i = 1; i < 8; i++) {
            s += r1[i][c];
            q += r2[i][c];
        }
        float dc = (cnt > 0) ? (float)cnt : 1.f;
        float m = s / dc;
        float v = fmaxf(q / dc - m * m, 0.f);
        gmv[c] = m;
        grs[c] = rsqrtf(v + 1e-5f);
    }
    __syncthreads();
    float m_ = gmv[c], r_ = grs[c];
    float mx = -3.0e38f;
    for (int n = start + slot; n < end; n += 8) mx = fmaxf(mx, (h[n * HC + c] - m_) * r_);
    r1[slot][c] = mx;
    __syncthreads();
    if (slot == 0) {
        for (int i = 1; i < 8; i++) mx = fmaxf(mx, r1[i][c]);
        pooled[c] = (cnt > 0) ? mx : 0.f;
    }
    __syncthreads();
    if (t < 2) {
        float o = linb[t];
        for (int k = 0; k < HC; k++) o += pooled[k] * linw[k * 2 + t];
        out[g * 2 + t] = o;
    }
}

// ---------------- launch ----------------

static inline size_t alignup(size_t v) { return (v + 255) & ~(size_t)255; }

extern "C" void kernel_launch(void* const* d_in, const int* in_sizes, int n_in,
                              void* d_out, int out_size, void* d_ws, size_t ws_size,
                              hipStream_t stream) {
    const int*   x      = (const int*)d_in[0];
    const int*   ei     = (const int*)d_in[1];
    const int*   batch  = (const int*)d_in[2];
    const float* emb    = (const float*)d_in[3];
    const float* w1     = (const float*)d_in[4];
    const float* g1wih  = (const float*)d_in[5];
    const float* g1whh  = (const float*)d_in[6];
    const float* g1bih  = (const float*)d_in[7];
    const float* g1bhh  = (const float*)d_in[8];
    const float* rel_w  = (const float*)d_in[9];
    const float* rel_b  = (const float*)d_in[10];
    const float* root_w = (const float*)d_in[11];
    const float* bn2g   = (const float*)d_in[12];
    const float* bn2b   = (const float*)d_in[13];
    const float* w3     = (const float*)d_in[14];
    const float* g3wih  = (const float*)d_in[15];
    const float* g3whh  = (const float*)d_in[16];
    const float* g3bih  = (const float*)d_in[17];
    const float* g3bhh  = (const float*)d_in[18];
    const float* lin3w  = (const float*)d_in[19];
    const float* lin3b  = (const float*)d_in[20];
    const float* w4     = (const float*)d_in[21];
    const float* b4     = (const float*)d_in[22];
    const float* lin4w  = (const float*)d_in[23];
    const float* lin4b  = (const float*)d_in[24];
    const float* sagelw = (const float*)d_in[25];
    const float* sagelb = (const float*)d_in[26];
    const float* sagerw = (const float*)d_in[27];
    const float* lin5w  = (const float*)d_in[28];
    const float* lin5b  = (const float*)d_in[29];
    const float* linw   = (const float*)d_in[30];
    const float* linb   = (const float*)d_in[31];

    const int* src = ei;
    const int* dst = ei + NE;

    char* ws = (char*)d_ws;
    size_t off = 0;
    int* deg = (int*)(ws + off); off = alignup(off + (size_t)NN * 4);
    int* cursor = (int*)(ws + off); off = alignup(off + (size_t)NN * 4);
    float* bnacc = (float*)(ws + off); off = alignup(off + 64 * 4);
    size_t zbytes = off;          // deg + cursor + bnacc zeroed
    int* bscan = (int*)(ws + off); off = alignup(off + 256 * 4);
    int* rowstart = (int*)(ws + off); off = alignup(off + (size_t)(NN + 1) * 4);
    float* dinv = (float*)(ws + off); off = alignup(off + (size_t)NN * 4);
    int* csr = (int*)(ws + off); off = alignup(off + (size_t)NE * 4);
    float* A = (float*)(ws + off); off = alignup(off + (size_t)NN * HC * 4);
    float* B = (float*)(ws + off); off = alignup(off + (size_t)NN * HC * 4);
    float* C = (float*)(ws + off); off = alignup(off + (size_t)NN * HC * 4);
    float* D = (float*)(ws + off); off = alignup(off + (size_t)NN * HC * 4);  // aggregated rows

    hipMemsetAsync(ws, 0, zbytes, stream);

    const int ngE = (NE + 255) / 256;
    const int ngN8 = NN / 8;            // 6250
    const int ngN64 = (NN + 63) / 64;   // 782 (gru v4 blocks)

    k_deg<<<ngE, 256, 0, stream>>>(dst, deg);
    k_scan1<<<NSCB, 256, 0, stream>>>(deg, bscan);
    k_scan2<<<1, 256, 0, stream>>>(bscan);
    k_scan3<<<NSCB, 256, 0, stream>>>(deg, bscan, rowstart, dinv);
    k_csr<<<ngE, 256, 0, stream>>>(src, dst, rowstart, cursor, csr);

    // AtomEncoder + B = h @ w1[0]; h = A
    k_atom_mm<<<ngN8, 256, 0, stream>>>(x, emb, w1, A, B);

    // conv1: GatedGraphConv(4, min); h = A; transformed feature ping-pongs B/C; D = agg scratch
    k_agg<0><<<ngN8, 256, 0, stream>>>(B, rowstart, csr, D);
    k_gru<false, 1><<<ngN64, 256, 0, stream>>>(D, A, g1wih, g1whh, g1bih, g1bhh, w1 + 1 * HC * HC, nullptr, C);
    k_agg<0><<<ngN8, 256, 0, stream>>>(C, rowstart, csr, D);
    k_gru<false, 1><<<ngN64, 256, 0, stream>>>(D, A, g1wih, g1whh, g1bih, g1bhh, w1 + 2 * HC * HC, nullptr, B);
    k_agg<0><<<ngN8, 256, 0, stream>>>(B, rowstart, csr, D);
    k_gru<false, 1><<<ngN64, 256, 0, stream>>>(D, A, g1wih, g1whh, g1bih, g1bhh, w1 + 3 * HC * HC, nullptr, C);
    k_agg<0><<<ngN8, 256, 0, stream>>>(C, rowstart, csr, D);
    k_gru<true, 0><<<ngN64, 256, 0, stream>>>(D, A, g1wih, g1whh, g1bih, g1bhh, nullptr, nullptr, nullptr);

    // conv2 + elu -> B (fused bn2 partial sums); bn apply + A = Bn @ w3[0]
    k_conv2<<<ngN8, 256, 0, stream>>>(A, B, rowstart, csr, rel_w, rel_b, root_w, bnacc);
    k_bnapply_mm<<<ngN8, 256, 0, stream>>>(B, bnacc, bn2g, bn2b, w3, A);

    // conv3: GatedGraphConv(5, mul); h = B; transformed feature ping-pongs A/C; last fuses relu(lin3) -> C
    k_agg<1><<<ngN8, 256, 0, stream>>>(A, rowstart, csr, D);
    k_gru<false, 1><<<ngN64, 256, 0, stream>>>(D, B, g3wih, g3whh, g3bih, g3bhh, w3 + 1 * HC * HC, nullptr, C);
    k_agg<1><<<ngN8, 256, 0, stream>>>(C, rowstart, csr, D);
    k_gru<false, 1><<<ngN64, 256, 0, stream>>>(D, B, g3wih, g3whh, g3bih, g3bhh, w3 + 2 * HC * HC, nullptr, A);
    k_agg<1><<<ngN8, 256, 0, stream>>>(A, rowstart, csr, D);
    k_gru<false, 1><<<ngN64, 256, 0, stream>>>(D, B, g3wih, g3whh, g3bih, g3bhh, w3 + 3 * HC * HC, nullptr, C);
    k_agg<1><<<ngN8, 256, 0, stream>>>(C, rowstart, csr, D);
    k_gru<false, 1><<<ngN64, 256, 0, stream>>>(D, B, g3wih, g3whh, g3bih, g3bhh, w3 + 4 * HC * HC, nullptr, A);
    k_agg<1><<<ngN8, 256, 0, stream>>>(A, rowstart, csr, D);
    k_gru<false, 2><<<ngN64, 256, 0, stream>>>(D, B, g3wih, g3whh, g3bih, g3bhh, lin3w, lin3b, C);

    // conv4: TAGConv K=7; h = C; acc = B; S ping-pongs A/C; out -> C
    k_mm_tag<<<ngN8, 256, 0, stream>>>(C, w4, B, A, dinv);
    {
        float* Scur = A;
        float* Snxt = C;
        for (int k = 1; k <= 6; k++) {
            k_tag<false><<<ngN8, 256, 0, stream>>>(Scur, Snxt, B, w4 + (size_t)k * HC * HC,
                                                   rowstart, csr, dinv, nullptr, nullptr, nullptr, nullptr);
            float* tmp = Scur; Scur = Snxt; Snxt = tmp;
        }
        k_tag<true><<<ngN8, 256, 0, stream>>>(Scur, nullptr, B, w4 + (size_t)7 * HC * HC,
                                              rowstart, csr, dinv, b4, lin4w, lin4b, C);
    }

    // conv5: SAGE var-aggr + softplus(lin5); h = C -> A
    k_sage<<<ngN8, 256, 0, stream>>>(C, A, rowstart, csr, sagelw, sagelb, sagerw, lin5w, lin5b);

    // bn5 (per-graph InstanceNorm) + max pool + final linear
    k_final<<<NG, 256, 0, stream>>>(A, batch, linw, linb, (float*)d_out);
}

// Round 13
// 678.836 us; speedup vs baseline: 1.2188x; 1.2188x over previous
//
#include <hip/hip_runtime.h>
#include <math.h>

#define NN 50000
#define NE 600000
#define NG 1000
#define HC 32
#define NSCB ((NN + 255) / 256)   // 196 scan blocks

__device__ __forceinline__ float softplusf(float s) {
    return fmaxf(s, 0.f) + log1pf(expf(-fabsf(s)));
}

__device__ __forceinline__ float4 shflx4(float4 v, int m) {
    v.x = __shfl_xor(v.x, m, 32);
    v.y = __shfl_xor(v.y, m, 32);
    v.z = __shfl_xor(v.z, m, 32);
    v.w = __shfl_xor(v.w, m, 32);
    return v;
}

__device__ __forceinline__ float dot4(float4 a, float4 b) {
    return a.x * b.x + a.y * b.y + a.z * b.z + a.w * b.w;
}

// ---------------- setup kernels ----------------

__global__ __launch_bounds__(256) void k_deg(const int* __restrict__ dst, int* __restrict__ deg) {
    int e = blockIdx.x * 256 + threadIdx.x;
    if (e < NE) atomicAdd(&deg[dst[e]], 1);
}

__global__ __launch_bounds__(256) void k_scan1(const int* __restrict__ deg, int* __restrict__ bscan) {
    __shared__ int sm[256];
    int t = threadIdx.x;
    int i = blockIdx.x * 256 + t;
    sm[t] = (i < NN) ? deg[i] : 0;
    __syncthreads();
    for (int o = 128; o > 0; o >>= 1) {
        if (t < o) sm[t] += sm[t + o];
        __syncthreads();
    }
    if (t == 0) bscan[blockIdx.x] = sm[0];
}

__global__ __launch_bounds__(256) void k_scan2(int* __restrict__ bscan) {
    __shared__ int sm[256];
    int t = threadIdx.x;
    int v = (t < NSCB) ? bscan[t] : 0;
    sm[t] = v;
    __syncthreads();
    for (int o = 1; o < 256; o <<= 1) {
        int u = (t >= o) ? sm[t - o] : 0;
        __syncthreads();
        sm[t] += u;
        __syncthreads();
    }
    if (t < NSCB) bscan[t] = sm[t] - v;  // exclusive
}

__global__ __launch_bounds__(256) void k_scan3(const int* __restrict__ deg, const int* __restrict__ bscan,
                                               int* __restrict__ rowstart, float* __restrict__ dinv) {
    __shared__ int sm[256];
    int t = threadIdx.x;
    int i = blockIdx.x * 256 + t;
    int d = (i < NN) ? deg[i] : 0;
    sm[t] = d;
    __syncthreads();
    for (int o = 1; o < 256; o <<= 1) {
        int u = (t >= o) ? sm[t - o] : 0;
        __syncthreads();
        sm[t] += u;
        __syncthreads();
    }
    int incl = sm[t];
    if (i < NN) {
        rowstart[i] = bscan[blockIdx.x] + incl - d;
        dinv[i] = d > 0 ? rsqrtf((float)d) : 0.f;
    }
    if (i == NN - 1) rowstart[NN] = bscan[blockIdx.x] + incl;
}

__global__ __launch_bounds__(256) void k_csr(const int* __restrict__ src, const int* __restrict__ dst,
                                             const int* __restrict__ rowstart, int* __restrict__ cursor,
                                             int* __restrict__ csr_src) {
    int e = blockIdx.x * 256 + threadIdx.x;
    if (e < NE) {
        int d = dst[e];
        int p = atomicAdd(&cursor[d], 1);
        csr_src[rowstart[d] + p] = src[e];
    }
}

// ---------------- AtomEncoder + first conv1 transform ----------------
__global__ __launch_bounds__(256) void k_atom_mm(const int* __restrict__ x, const float* __restrict__ emb,
                                                 const float* __restrict__ W, float* __restrict__ h,
                                                 float* __restrict__ hw) {
    __shared__ float wl[HC * HC];
    __shared__ float il[8][HC];
    int t = threadIdx.x;
    ((float4*)wl)[t] = ((const float4*)W)[t];
    int slot = t >> 5, c = t & 31;
    int n = blockIdx.x * 8 + slot;
    float s = 0.f;
#pragma unroll
    for (int j = 0; j < 9; j++) {
        int v = x[n * 9 + j];
        s += emb[(j * 100 + v) * HC + c];
    }
    __syncthreads();   // staging barrier (weights)
    h[n * HC + c] = s;
    il[slot][c] = s;   // intra-wave sharing only below
    float o = 0.f;
#pragma unroll
    for (int k = 0; k < HC; k++) o += il[slot][k] * wl[k * HC + c];
    hw[n * HC + c] = o;
}

// ---------------- aggregation only: no LDS, no barrier, low VGPR; 512 thr / 16 nodes ----------------
template <int AGGR>
__global__ __launch_bounds__(512) void k_agg(const float* __restrict__ hw,
                                             const int* __restrict__ rowstart, const int* __restrict__ csr_src,
                                             float* __restrict__ aout) {
    int t = threadIdx.x;
    int slot = t >> 5, c = t & 31;
    int sub = c >> 3;
    int ch4 = (c & 7) * 4;
    int n = blockIdx.x * 16 + slot;
    int rs = rowstart[n], re = rowstart[n + 1];
    float4 a4;
    if (AGGR == 0) {
        float4 m4 = make_float4(3.0e38f, 3.0e38f, 3.0e38f, 3.0e38f);
        for (int base = rs; base < re; base += 32) {
            int cnt = min(re - base, 32);
            int myidx = (c < cnt) ? csr_src[base + c] : 0;
#pragma unroll
            for (int jj = 0; jj < 8; jj++) {
                int r = jj * 4 + sub;
                int sidx = __shfl(myidx, r, 32);
                if (r < cnt) {
                    float4 v = *(const float4*)(hw + sidx * HC + ch4);
                    m4.x = fminf(m4.x, v.x); m4.y = fminf(m4.y, v.y);
                    m4.z = fminf(m4.z, v.z); m4.w = fminf(m4.w, v.w);
                }
            }
        }
        float4 o4 = shflx4(m4, 8);
        m4.x = fminf(m4.x, o4.x); m4.y = fminf(m4.y, o4.y); m4.z = fminf(m4.z, o4.z); m4.w = fminf(m4.w, o4.w);
        o4 = shflx4(m4, 16);
        m4.x = fminf(m4.x, o4.x); m4.y = fminf(m4.y, o4.y); m4.z = fminf(m4.z, o4.z); m4.w = fminf(m4.w, o4.w);
        a4 = (re > rs) ? m4 : make_float4(0.f, 0.f, 0.f, 0.f);
    } else {
        float4 lg = make_float4(0.f, 0.f, 0.f, 0.f);
        int4 ng = make_int4(0, 0, 0, 0);
        for (int base = rs; base < re; base += 32) {
            int cnt = min(re - base, 32);
            int myidx = (c < cnt) ? csr_src[base + c] : 0;
#pragma unroll
            for (int jj = 0; jj < 8; jj++) {
                int r = jj * 4 + sub;
                int sidx = __shfl(myidx, r, 32);
                if (r < cnt) {
                    float4 v = *(const float4*)(hw + sidx * HC + ch4);
                    ng.x += (v.x < 0.f) ? 1 : 0; ng.y += (v.y < 0.f) ? 1 : 0;
                    ng.z += (v.z < 0.f) ? 1 : 0; ng.w += (v.w < 0.f) ? 1 : 0;
                    lg.x += __logf(fabsf(v.x)); lg.y += __logf(fabsf(v.y));
                    lg.z += __logf(fabsf(v.z)); lg.w += __logf(fabsf(v.w));
                }
            }
        }
        float4 o4 = shflx4(lg, 8);
        lg.x += o4.x; lg.y += o4.y; lg.z += o4.z; lg.w += o4.w;
        o4 = shflx4(lg, 16);
        lg.x += o4.x; lg.y += o4.y; lg.z += o4.z; lg.w += o4.w;
        ng.x += __shfl_xor(ng.x, 8, 32); ng.y += __shfl_xor(ng.y, 8, 32);
        ng.z += __shfl_xor(ng.z, 8, 32); ng.w += __shfl_xor(ng.w, 8, 32);
        ng.x += __shfl_xor(ng.x, 16, 32); ng.y += __shfl_xor(ng.y, 16, 32);
        ng.z += __shfl_xor(ng.z, 16, 32); ng.w += __shfl_xor(ng.w, 16, 32);
        if (re > rs) {
            float ex = __expf(lg.x); a4.x = (ng.x & 1) ? -ex : ex;
            ex = __expf(lg.y); a4.y = (ng.y & 1) ? -ex : ex;
            ex = __expf(lg.z); a4.z = (ng.z & 1) ? -ex : ex;
            ex = __expf(lg.w); a4.w = (ng.w & 1) ? -ex : ex;
        } else {
            a4 = make_float4(0.f, 0.f, 0.f, 0.f);
        }
    }
    if (c < 8) *(float4*)(aout + n * HC + ch4) = a4;
}

// ---------------- GRU update v3: node-blocked (4 nodes/thread), b128 LDS, capped unroll ----------------
// 256 threads = 8 slots x 32 channels; block covers 32 nodes. Weights row-contiguous in LDS,
// stride 36 dwords. unroll 1 on k4 loops keeps VGPR < 128 (R10 lesson: full unroll -> 236 VGPR).
// EPI: 0 none, 1 h@Wn, 2 relu(h@Wn + nb).
#define WS 36   // dword stride for weight rows (9 float4)
template <bool POSTRELU, int EPI>
__global__ __launch_bounds__(256) void k_gru(const float* __restrict__ aIn, float* __restrict__ h,
                                             const float* __restrict__ wih, const float* __restrict__ whh,
                                             const float* __restrict__ bih, const float* __restrict__ bhh,
                                             const float* __restrict__ Wn, const float* __restrict__ nb,
                                             float* __restrict__ out_next) {
    __shared__ float wiL[96 * WS];
    __shared__ float whL[96 * WS];
    __shared__ float wnT[EPI > 0 ? 32 * WS : 4];
    __shared__ float al[32][HC];
    __shared__ float hl[32][HC];
    int t = threadIdx.x;
    // stage wi/wh row-contiguous (768 float4 each)
    for (int i4 = t; i4 < 768; i4 += 256) {
        int row = i4 >> 3, k4 = i4 & 7;
        ((float4*)wiL)[row * 9 + k4] = ((const float4*)wih)[i4];
        ((float4*)whL)[row * 9 + k4] = ((const float4*)whh)[i4];
    }
    if (EPI > 0) {
        // transpose Wn[k][c] -> wnT[c][k] (stride WS)
        int i = t * 4;
        int k = i >> 5, c0 = i & 31;
        float4 v = ((const float4*)Wn)[t];
        wnT[(c0 + 0) * WS + k] = v.x;
        wnT[(c0 + 1) * WS + k] = v.y;
        wnT[(c0 + 2) * WS + k] = v.z;
        wnT[(c0 + 3) * WS + k] = v.w;
    }
    int slot = t >> 5, c = t & 31;
    int nb0 = blockIdx.x * 32 + slot * 4;
    float b_ir = bih[c], b_iz = bih[HC + c], b_in = bih[2 * HC + c];
    float b_hr = bhh[c], b_hz = bhh[HC + c], b_hn = bhh[2 * HC + c];
    float nbv = (EPI == 2) ? nb[c] : 0.f;
    float hv[4];
#pragma unroll
    for (int j = 0; j < 4; j++) {
        int n = nb0 + j;
        float aa = 0.f, hh = 0.f;
        if (n < NN) {
            aa = aIn[n * HC + c];
            hh = h[n * HC + c];
        }
        hv[j] = hh;
        al[slot * 4 + j][c] = aa;
        hl[slot * 4 + j][c] = hh;
    }
    __syncthreads();   // single barrier: weights staged

    float aIR[4], aIZ[4], aIN[4], aHR[4], aHZ[4], aHN[4];
#pragma unroll
    for (int j = 0; j < 4; j++) {
        aIR[j] = b_ir; aIZ[j] = b_iz; aIN[j] = b_in;
        aHR[j] = b_hr; aHZ[j] = b_hz; aHN[j] = b_hn;
    }
    const float4* wi4 = (const float4*)wiL;
    const float4* wh4 = (const float4*)whL;
    int r0 = c * 9, r1 = (32 + c) * 9, r2 = (64 + c) * 9;
#pragma unroll 1
    for (int k4 = 0; k4 < 8; k4++) {
        float4 wir = wi4[r0 + k4], wiz = wi4[r1 + k4], win = wi4[r2 + k4];
        float4 whr = wh4[r0 + k4], whz = wh4[r1 + k4], whn = wh4[r2 + k4];
#pragma unroll
        for (int j = 0; j < 4; j++) {
            float4 av = *(const float4*)&al[slot * 4 + j][k4 * 4];
            float4 hb = *(const float4*)&hl[slot * 4 + j][k4 * 4];
            aIR[j] += dot4(av, wir);
            aIZ[j] += dot4(av, wiz);
            aIN[j] += dot4(av, win);
            aHR[j] += dot4(hb, whr);
            aHZ[j] += dot4(hb, whz);
            aHN[j] += dot4(hb, whn);
        }
    }
    float hn[4];
#pragma unroll
    for (int j = 0; j < 4; j++) {
        float r = 1.f / (1.f + __expf(-(aIR[j] + aHR[j])));
        float z = 1.f / (1.f + __expf(-(aIZ[j] + aHZ[j])));
        float nnv = tanhf(aIN[j] + r * aHN[j]);
        float v = (1.f - z) * nnv + z * hv[j];
        if (POSTRELU) v = fmaxf(v, 0.f);
        hn[j] = v;
        int n = nb0 + j;
        if (n < NN) h[n * HC + c] = v;
    }
    if (EPI > 0) {
        // reuse al for h_new (intra-half-wave, lockstep -> no barrier)
#pragma unroll
        for (int j = 0; j < 4; j++) al[slot * 4 + j][c] = hn[j];
        float accE[4];
#pragma unroll
        for (int j = 0; j < 4; j++) accE[j] = (EPI == 2) ? nbv : 0.f;
        const float4* wn4 = (const float4*)wnT;
        int rc = c * 9;
#pragma unroll 1
        for (int k4 = 0; k4 < 8; k4++) {
            float4 wv = wn4[rc + k4];
#pragma unroll
            for (int j = 0; j < 4; j++) {
                float4 hb = *(const float4*)&al[slot * 4 + j][k4 * 4];
                accE[j] += dot4(hb, wv);
            }
        }
#pragma unroll
        for (int j = 0; j < 4; j++) {
            float o = accE[j];
            if (EPI == 2) o = fmaxf(o, 0.f);
            int n = nb0 + j;
            if (n < NN) out_next[n * HC + c] = o;
        }
    }
}

// ---------------- conv2: GraphConv sum + two matmuls + ELU ----------------
__global__ __launch_bounds__(256) void k_conv2(const float* __restrict__ h, float* __restrict__ out,
                                               const int* __restrict__ rowstart, const int* __restrict__ csr_src,
                                               const float* __restrict__ rel_w, const float* __restrict__ rel_b,
                                               const float* __restrict__ root_w) {
    __shared__ float rw[HC * HC], ow[HC * HC];
    __shared__ float sl[8][HC], hl[8][HC];
    int t = threadIdx.x;
    ((float4*)rw)[t] = ((const float4*)rel_w)[t];
    ((float4*)ow)[t] = ((const float4*)root_w)[t];
    int slot = t >> 5, c = t & 31;
    int sub = c >> 3;
    int ch4 = (c & 7) * 4;
    int n = blockIdx.x * 8 + slot;
    int rs = rowstart[n], re = rowstart[n + 1];
    __syncthreads();   // staging barrier
    float4 s4 = make_float4(0.f, 0.f, 0.f, 0.f);
    for (int base = rs; base < re; base += 32) {
        int cnt = min(re - base, 32);
        int myidx = (c < cnt) ? csr_src[base + c] : 0;
#pragma unroll
        for (int jj = 0; jj < 8; jj++) {
            int r = jj * 4 + sub;
            int sidx = __shfl(myidx, r, 32);
            if (r < cnt) {
                float4 v = *(const float4*)(h + sidx * HC + ch4);
                s4.x += v.x; s4.y += v.y; s4.z += v.z; s4.w += v.w;
            }
        }
    }
    float4 o4 = shflx4(s4, 8);
    s4.x += o4.x; s4.y += o4.y; s4.z += o4.z; s4.w += o4.w;
    o4 = shflx4(s4, 16);
    s4.x += o4.x; s4.y += o4.y; s4.z += o4.z; s4.w += o4.w;
    if (c < 8) *(float4*)&sl[slot][ch4] = s4;
    float hv = h[n * HC + c];
    hl[slot][c] = hv;
    float o = rel_b[c];
#pragma unroll
    for (int k = 0; k < HC; k++) o += sl[slot][k] * rw[k * HC + c] + hl[slot][k] * ow[k * HC + c];
    o = (o > 0.f) ? o : expm1f(o);
    out[n * HC + c] = o;
}

// ---------------- bn2 reduce (256 blocks -> bounded atomic fan-in) ----------------
__global__ __launch_bounds__(256) void k_bnred(const float* __restrict__ h, float* __restrict__ acc) {
    __shared__ float ls[8][HC], lq[8][HC];
    int t = threadIdx.x, slot = t >> 5, c = t & 31;
    float s = 0.f, q = 0.f;
    for (int n = blockIdx.x * 8 + slot; n < NN; n += gridDim.x * 8) {
        float v = h[n * HC + c];
        s += v;
        q += v * v;
    }
    ls[slot][c] = s;
    lq[slot][c] = q;
    __syncthreads();   // cross-slot reduction: barrier required
    if (slot == 0) {
        for (int i = 1; i < 8; i++) {
            s += ls[i][c];
            q += lq[i][c];
        }
        atomicAdd(&acc[c], s);
        atomicAdd(&acc[HC + c], q);
    }
}

// ---------------- bn2 apply (in place) + first conv3 transform ----------------
__global__ __launch_bounds__(256) void k_bnapply_mm(float* __restrict__ h, const float* __restrict__ acc,
                                                    const float* __restrict__ g_, const float* __restrict__ b,
                                                    const float* __restrict__ W, float* __restrict__ out) {
    __shared__ float wl[HC * HC];
    __shared__ float il[8][HC];
    int t = threadIdx.x;
    ((float4*)wl)[t] = ((const float4*)W)[t];
    int slot = t >> 5, c = t & 31;
    int n = blockIdx.x * 8 + slot;
    float mu = acc[c] * (1.f / NN);
    float var = acc[HC + c] * (1.f / NN) - mu * mu;
    float v = (h[n * HC + c] - mu) * rsqrtf(var + 1e-5f) * g_[c] + b[c];
    __syncthreads();   // staging barrier
    h[n * HC + c] = v;
    il[slot][c] = v;
    float s = 0.f;
#pragma unroll
    for (int k = 0; k < HC; k++) s += il[slot][k] * wl[k * HC + c];
    out[n * HC + c] = s;
}

// ---------------- conv4 initial: acc = h@W0, S = dinv*h ----------------
__global__ __launch_bounds__(256) void k_mm_tag(const float* __restrict__ in, const float* __restrict__ W,
                                                float* __restrict__ acc, float* __restrict__ S,
                                                const float* __restrict__ dinv) {
    __shared__ float wl[HC * HC];
    __shared__ float il[8][HC];
    int t = threadIdx.x;
    ((float4*)wl)[t] = ((const float4*)W)[t];
    int slot = t >> 5, c = t & 31;
    int n = blockIdx.x * 8 + slot;
    float v = in[n * HC + c];
    __syncthreads();   // staging barrier
    il[slot][c] = v;
    S[n * HC + c] = dinv[n] * v;
    float s = 0.f;
#pragma unroll
    for (int k = 0; k < HC; k++) s += il[slot][k] * wl[k * HC + c];
    acc[n * HC + c] = s;
}

// ---------------- TAG hop on pre-scaled S; LAST fuses b4 + softplus(lin4) ----------------
template <bool LAST>
__global__ __launch_bounds__(256) void k_tag(const float* __restrict__ S, float* __restrict__ Snew,
                                             float* __restrict__ acc, const float* __restrict__ Wk,
                                             const int* __restrict__ rowstart, const int* __restrict__ csr_src,
                                             const float* __restrict__ dinv,
                                             const float* __restrict__ b4, const float* __restrict__ l4w,
                                             const float* __restrict__ l4b, float* __restrict__ out) {
    __shared__ float wl[HC * HC];
    __shared__ float w2[LAST ? HC * HC : 1];
    __shared__ float cl[8][HC];
    int t = threadIdx.x;
    ((float4*)wl)[t] = ((const float4*)Wk)[t];
    if (LAST) ((float4*)w2)[t] = ((const float4*)l4w)[t];
    int slot = t >> 5, c = t & 31;
    int sub = c >> 3;
    int ch4 = (c & 7) * 4;
    int n = blockIdx.x * 8 + slot;
    int rs = rowstart[n], re = rowstart[n + 1];
    __syncthreads();   // staging barrier
    float4 s4 = make_float4(0.f, 0.f, 0.f, 0.f);
    for (int base = rs; base < re; base += 32) {
        int cnt = min(re - base, 32);
        int myidx = (c < cnt) ? csr_src[base + c] : 0;
#pragma unroll
        for (int jj = 0; jj < 8; jj++) {
            int r = jj * 4 + sub;
            int sidx = __shfl(myidx, r, 32);
            if (r < cnt) {
                float4 v = *(const float4*)(S + sidx * HC + ch4);
                s4.x += v.x; s4.y += v.y; s4.z += v.z; s4.w += v.w;
            }
        }
    }
    float4 o4 = shflx4(s4, 8);
    s4.x += o4.x; s4.y += o4.y; s4.z += o4.z; s4.w += o4.w;
    o4 = shflx4(s4, 16);
    s4.x += o4.x; s4.y += o4.y; s4.z += o4.z; s4.w += o4.w;
    float di = dinv[n];
    if (c < 8) {
        float4 cn4 = make_float4(di * s4.x, di * s4.y, di * s4.z, di * s4.w);
        *(float4*)&cl[slot][ch4] = cn4;
        if (!LAST) {
            float4 sn4 = make_float4(di * cn4.x, di * cn4.y, di * cn4.z, di * cn4.w);
            *(float4*)(Snew + n * HC + ch4) = sn4;
        }
    }
    float o = 0.f;
#pragma unroll
    for (int k = 0; k < HC; k++) o += cl[slot][k] * wl[k * HC + c];
    if (!LAST) {
        acc[n * HC + c] += o;
    } else {
        float tmp = acc[n * HC + c] + o + b4[c];
        cl[slot][c] = tmp;   // intra-wave
        float o2 = l4b[c];
#pragma unroll
        for (int k = 0; k < HC; k++) o2 += cl[slot][k] * w2[k * HC + c];
        out[n * HC + c] = softplusf(o2);
    }
}

// ---------------- conv5: SAGE var-aggr + fused softplus(lin5) ----------------
__global__ __launch_bounds__(256) void k_sage(const float* __restrict__ h, float* __restrict__ out,
                                              const int* __restrict__ rowstart, const int* __restrict__ csr_src,
                                              const float* __restrict__ lw, const float* __restrict__ lb,
                                              const float* __restrict__ rw_, const float* __restrict__ l5w,
                                              const float* __restrict__ l5b) {
    __shared__ float wl[HC * HC], wr[HC * HC], w5[HC * HC];
    __shared__ float vl[8][HC], hl[8][HC];
    int t = threadIdx.x;
    ((float4*)wl)[t] = ((const float4*)lw)[t];
    ((float4*)wr)[t] = ((const float4*)rw_)[t];
    ((float4*)w5)[t] = ((const float4*)l5w)[t];
    int slot = t >> 5, c = t & 31;
    int sub = c >> 3;
    int ch4 = (c & 7) * 4;
    int n = blockIdx.x * 8 + slot;
    int rs = rowstart[n], re = rowstart[n + 1];
    __syncthreads();   // staging barrier
    float4 s4 = make_float4(0.f, 0.f, 0.f, 0.f);
    float4 q4 = make_float4(0.f, 0.f, 0.f, 0.f);
    for (int base = rs; base < re; base += 32) {
        int cnt = min(re - base, 32);
        int myidx = (c < cnt) ? csr_src[base + c] : 0;
#pragma unroll
        for (int jj = 0; jj < 8; jj++) {
            int r = jj * 4 + sub;
            int sidx = __shfl(myidx, r, 32);
            if (r < cnt) {
                float4 v = *(const float4*)(h + sidx * HC + ch4);
                s4.x += v.x; s4.y += v.y; s4.z += v.z; s4.w += v.w;
                q4.x += v.x * v.x; q4.y += v.y * v.y; q4.z += v.z * v.z; q4.w += v.w * v.w;
            }
        }
    }
    float4 o4 = shflx4(s4, 8);
    s4.x += o4.x; s4.y += o4.y; s4.z += o4.z; s4.w += o4.w;
    o4 = shflx4(s4, 16);
    s4.x += o4.x; s4.y += o4.y; s4.z += o4.z; s4.w += o4.w;
    o4 = shflx4(q4, 8);
    q4.x += o4.x; q4.y += o4.y; q4.z += o4.z; q4.w += o4.w;
    o4 = shflx4(q4, 16);
    q4.x += o4.x; q4.y += o4.y; q4.z += o4.z; q4.w += o4.w;
    float dc = fmaxf((float)(re - rs), 1.f);
    float inv = 1.f / dc;
    if (c < 8) {
        float4 var4;
        float m0 = s4.x * inv, m1 = s4.y * inv, m2 = s4.z * inv, m3 = s4.w * inv;
        var4.x = q4.x * inv - m0 * m0;
        var4.y = q4.y * inv - m1 * m1;
        var4.z = q4.z * inv - m2 * m2;
        var4.w = q4.w * inv - m3 * m3;
        *(float4*)&vl[slot][ch4] = var4;
    }
    float hv = h[n * HC + c];
    hl[slot][c] = hv;
    float o = lb[c];
#pragma unroll
    for (int k = 0; k < HC; k++) o += vl[slot][k] * wl[k * HC + c] + hl[slot][k] * wr[k * HC + c];
    vl[slot][c] = o;   // intra-wave
    float o2 = l5b[c];
#pragma unroll
    for (int k = 0; k < HC; k++) o2 += vl[slot][k] * w5[k * HC + c];
    out[n * HC + c] = softplusf(o2);
}

// ---------------- per-graph InstanceNorm + global max pool + final linear ----------------
__global__ __launch_bounds__(256) void k_final(const float* __restrict__ h, const int* __restrict__ batch,
                                               const float* __restrict__ linw, const float* __restrict__ linb,
                                               float* __restrict__ out) {
    __shared__ float r1[8][HC];
    __shared__ float r2[8][HC];
    __shared__ float gmv[HC], grs[HC], pooled[HC];
    int g = blockIdx.x;
    int t = threadIdx.x, slot = t >> 5, c = t & 31;
    int lo = 0, hi = NN;
    while (lo < hi) {
        int mid = (lo + hi) >> 1;
        if (batch[mid] < g) lo = mid + 1;
        else hi = mid;
    }
    int start = lo;
    hi = NN;
    while (lo < hi) {
        int mid = (lo + hi) >> 1;
        if (batch[mid] <= g) lo = mid + 1;
        else hi = mid;
    }
    int end = lo;
    int cnt = end - start;
    float s = 0.f, q = 0.f;
    for (int n = start + slot; n < end; n += 8) {
        float v = h[n * HC + c];
        s += v;
        q += v * v;
    }
    r1[slot][c] = s;
    r2[slot][c] = q;
    __syncthreads();
    if (slot == 0) {
        for (int i = 1; i < 8; i++) {
            s += r1[i][c];
            q += r2[i][c];
        }
        float dc = (cnt > 0) ? (float)cnt : 1.f;
        float m = s / dc;
        float v = fmaxf(q / dc - m * m, 0.f);
        gmv[c] = m;
        grs[c] = rsqrtf(v + 1e-5f);
    }
    __syncthreads();
    float m_ = gmv[c], r_ = grs[c];
    float mx = -3.0e38f;
    for (int n = start + slot; n < end; n += 8) mx = fmaxf(mx, (h[n * HC + c] - m_) * r_);
    r1[slot][c] = mx;
    __syncthreads();
    if (slot == 0) {
        for (int i = 1; i < 8; i++) mx = fmaxf(mx, r1[i][c]);
        pooled[c] = (cnt > 0) ? mx : 0.f;
    }
    __syncthreads();
    if (t < 2) {
        float o = linb[t];
        for (int k = 0; k < HC; k++) o += pooled[k] * linw[k * 2 + t];
        out[g * 2 + t] = o;
    }
}

// ---------------- launch ----------------

static inline size_t alignup(size_t v) { return (v + 255) & ~(size_t)255; }

extern "C" void kernel_launch(void* const* d_in, const int* in_sizes, int n_in,
                              void* d_out, int out_size, void* d_ws, size_t ws_size,
                              hipStream_t stream) {
    const int*   x      = (const int*)d_in[0];
    const int*   ei     = (const int*)d_in[1];
    const int*   batch  = (const int*)d_in[2];
    const float* emb    = (const float*)d_in[3];
    const float* w1     = (const float*)d_in[4];
    const float* g1wih  = (const float*)d_in[5];
    const float* g1whh  = (const float*)d_in[6];
    const float* g1bih  = (const float*)d_in[7];
    const float* g1bhh  = (const float*)d_in[8];
    const float* rel_w  = (const float*)d_in[9];
    const float* rel_b  = (const float*)d_in[10];
    const float* root_w = (const float*)d_in[11];
    const float* bn2g   = (const float*)d_in[12];
    const float* bn2b   = (const float*)d_in[13];
    const float* w3     = (const float*)d_in[14];
    const float* g3wih  = (const float*)d_in[15];
    const float* g3whh  = (const float*)d_in[16];
    const float* g3bih  = (const float*)d_in[17];
    const float* g3bhh  = (const float*)d_in[18];
    const float* lin3w  = (const float*)d_in[19];
    const float* lin3b  = (const float*)d_in[20];
    const float* w4     = (const float*)d_in[21];
    const float* b4     = (const float*)d_in[22];
    const float* lin4w  = (const float*)d_in[23];
    const float* lin4b  = (const float*)d_in[24];
    const float* sagelw = (const float*)d_in[25];
    const float* sagelb = (const float*)d_in[26];
    const float* sagerw = (const float*)d_in[27];
    const float* lin5w  = (const float*)d_in[28];
    const float* lin5b  = (const float*)d_in[29];
    const float* linw   = (const float*)d_in[30];
    const float* linb   = (const float*)d_in[31];

    const int* src = ei;
    const int* dst = ei + NE;

    char* ws = (char*)d_ws;
    size_t off = 0;
    int* deg = (int*)(ws + off); off = alignup(off + (size_t)NN * 4);
    int* cursor = (int*)(ws + off); off = alignup(off + (size_t)NN * 4);
    float* bnacc = (float*)(ws + off); off = alignup(off + 64 * 4);
    size_t zbytes = off;          // deg + cursor + bnacc zeroed
    int* bscan = (int*)(ws + off); off = alignup(off + 256 * 4);
    int* rowstart = (int*)(ws + off); off = alignup(off + (size_t)(NN + 1) * 4);
    float* dinv = (float*)(ws + off); off = alignup(off + (size_t)NN * 4);
    int* csr = (int*)(ws + off); off = alignup(off + (size_t)NE * 4);
    float* A = (float*)(ws + off); off = alignup(off + (size_t)NN * HC * 4);
    float* B = (float*)(ws + off); off = alignup(off + (size_t)NN * HC * 4);
    float* C = (float*)(ws + off); off = alignup(off + (size_t)NN * HC * 4);
    float* D = (float*)(ws + off); off = alignup(off + (size_t)NN * HC * 4);  // aggregated rows

    hipMemsetAsync(ws, 0, zbytes, stream);

    const int ngE = (NE + 255) / 256;
    const int ngN8 = NN / 8;            // 6250
    const int ngN16 = NN / 16;          // 3125 (512-thread k_agg blocks)
    const int ngN32 = (NN + 31) / 32;   // 1563 (gru v3 blocks)

    k_deg<<<ngE, 256, 0, stream>>>(dst, deg);
    k_scan1<<<NSCB, 256, 0, stream>>>(deg, bscan);
    k_scan2<<<1, 256, 0, stream>>>(bscan);
    k_scan3<<<NSCB, 256, 0, stream>>>(deg, bscan, rowstart, dinv);
    k_csr<<<ngE, 256, 0, stream>>>(src, dst, rowstart, cursor, csr);

    // AtomEncoder + B = h @ w1[0]; h = A
    k_atom_mm<<<ngN8, 256, 0, stream>>>(x, emb, w1, A, B);

    // conv1: GatedGraphConv(4, min); h = A; transformed feature ping-pongs B/C; D = agg scratch
    k_agg<0><<<ngN16, 512, 0, stream>>>(B, rowstart, csr, D);
    k_gru<false, 1><<<ngN32, 256, 0, stream>>>(D, A, g1wih, g1whh, g1bih, g1bhh, w1 + 1 * HC * HC, nullptr, C);
    k_agg<0><<<ngN16, 512, 0, stream>>>(C, rowstart, csr, D);
    k_gru<false, 1><<<ngN32, 256, 0, stream>>>(D, A, g1wih, g1whh, g1bih, g1bhh, w1 + 2 * HC * HC, nullptr, B);
    k_agg<0><<<ngN16, 512, 0, stream>>>(B, rowstart, csr, D);
    k_gru<false, 1><<<ngN32, 256, 0, stream>>>(D, A, g1wih, g1whh, g1bih, g1bhh, w1 + 3 * HC * HC, nullptr, C);
    k_agg<0><<<ngN16, 512, 0, stream>>>(C, rowstart, csr, D);
    k_gru<true, 0><<<ngN32, 256, 0, stream>>>(D, A, g1wih, g1whh, g1bih, g1bhh, nullptr, nullptr, nullptr);

    // conv2 + elu -> B; bn2 stats (256-block fan-in); bn apply + A = Bn @ w3[0]
    k_conv2<<<ngN8, 256, 0, stream>>>(A, B, rowstart, csr, rel_w, rel_b, root_w);
    k_bnred<<<256, 256, 0, stream>>>(B, bnacc);
    k_bnapply_mm<<<ngN8, 256, 0, stream>>>(B, bnacc, bn2g, bn2b, w3, A);

    // conv3: GatedGraphConv(5, mul); h = B; transformed feature ping-pongs A/C; last fuses relu(lin3) -> C
    k_agg<1><<<ngN16, 512, 0, stream>>>(A, rowstart, csr, D);
    k_gru<false, 1><<<ngN32, 256, 0, stream>>>(D, B, g3wih, g3whh, g3bih, g3bhh, w3 + 1 * HC * HC, nullptr, C);
    k_agg<1><<<ngN16, 512, 0, stream>>>(C, rowstart, csr, D);
    k_gru<false, 1><<<ngN32, 256, 0, stream>>>(D, B, g3wih, g3whh, g3bih, g3bhh, w3 + 2 * HC * HC, nullptr, A);
    k_agg<1><<<ngN16, 512, 0, stream>>>(A, rowstart, csr, D);
    k_gru<false, 1><<<ngN32, 256, 0, stream>>>(D, B, g3wih, g3whh, g3bih, g3bhh, w3 + 3 * HC * HC, nullptr, C);
    k_agg<1><<<ngN16, 512, 0, stream>>>(C, rowstart, csr, D);
    k_gru<false, 1><<<ngN32, 256, 0, stream>>>(D, B, g3wih, g3whh, g3bih, g3bhh, w3 + 4 * HC * HC, nullptr, A);
    k_agg<1><<<ngN16, 512, 0, stream>>>(A, rowstart, csr, D);
    k_gru<false, 2><<<ngN32, 256, 0, stream>>>(D, B, g3wih, g3whh, g3bih, g3bhh, lin3w, lin3b, C);

    // conv4: TAGConv K=7; h = C; acc = B; S ping-pongs A/C; out -> C
    k_mm_tag<<<ngN8, 256, 0, stream>>>(C, w4, B, A, dinv);
    {
        float* Scur = A;
        float* Snxt = C;
        for (int k = 1; k <= 6; k++) {
            k_tag<false><<<ngN8, 256, 0, stream>>>(Scur, Snxt, B, w4 + (size_t)k * HC * HC,
                                                   rowstart, csr, dinv, nullptr, nullptr, nullptr, nullptr);
            float* tmp = Scur; Scur = Snxt; Snxt = tmp;
        }
        k_tag<true><<<ngN8, 256, 0, stream>>>(Scur, nullptr, B, w4 + (size_t)7 * HC * HC,
                                              rowstart, csr, dinv, b4, lin4w, lin4b, C);
    }

    // conv5: SAGE var-aggr + softplus(lin5); h = C -> A
    k_sage<<<ngN8, 256, 0, stream>>>(C, A, rowstart, csr, sagelw, sagelb, sagerw, lin5w, lin5b);

    // bn5 (per-graph InstanceNorm) + max pool + final linear
    k_final<<<NG, 256, 0, stream>>>(A, batch, linw, linb, (float*)d_out);
}

// Round 14
// 672.259 us; speedup vs baseline: 1.2307x; 1.0098x over previous
//
#include <hip/hip_runtime.h>
#include <math.h>

#define NN 50000
#define NE 600000
#define NG 1000
#define HC 32
#define NSCB ((NN + 255) / 256)   // 196 scan blocks

__device__ __forceinline__ float softplusf(float s) {
    return fmaxf(s, 0.f) + log1pf(expf(-fabsf(s)));
}

__device__ __forceinline__ float4 shflx4(float4 v, int m) {
    v.x = __shfl_xor(v.x, m, 32);
    v.y = __shfl_xor(v.y, m, 32);
    v.z = __shfl_xor(v.z, m, 32);
    v.w = __shfl_xor(v.w, m, 32);
    return v;
}

__device__ __forceinline__ float dot4(float4 a, float4 b) {
    return a.x * b.x + a.y * b.y + a.z * b.z + a.w * b.w;
}

// ---------------- setup kernels ----------------

__global__ __launch_bounds__(256) void k_deg(const int* __restrict__ dst, int* __restrict__ deg) {
    int e = blockIdx.x * 256 + threadIdx.x;
    if (e < NE) atomicAdd(&deg[dst[e]], 1);
}

__global__ __launch_bounds__(256) void k_scan1(const int* __restrict__ deg, int* __restrict__ bscan) {
    __shared__ int sm[256];
    int t = threadIdx.x;
    int i = blockIdx.x * 256 + t;
    sm[t] = (i < NN) ? deg[i] : 0;
    __syncthreads();
    for (int o = 128; o > 0; o >>= 1) {
        if (t < o) sm[t] += sm[t + o];
        __syncthreads();
    }
    if (t == 0) bscan[blockIdx.x] = sm[0];
}

// local scan + parallel prefix over raw block sums (scan2 folded in)
__global__ __launch_bounds__(256) void k_scan3(const int* __restrict__ deg, const int* __restrict__ bscan,
                                               int* __restrict__ rowstart, float* __restrict__ dinv) {
    __shared__ int sm[256];
    __shared__ int pre[256];
    int t = threadIdx.x;
    pre[t] = (t < blockIdx.x) ? bscan[t] : 0;   // blockIdx.x <= 195 < NSCB
    __syncthreads();
    for (int o = 128; o > 0; o >>= 1) {
        if (t < o) pre[t] += pre[t + o];
        __syncthreads();
    }
    int base0 = pre[0];
    int i = blockIdx.x * 256 + t;
    int d = (i < NN) ? deg[i] : 0;
    sm[t] = d;
    __syncthreads();
    for (int o = 1; o < 256; o <<= 1) {
        int u = (t >= o) ? sm[t - o] : 0;
        __syncthreads();
        sm[t] += u;
        __syncthreads();
    }
    int incl = sm[t];
    if (i < NN) {
        rowstart[i] = base0 + incl - d;
        dinv[i] = d > 0 ? rsqrtf((float)d) : 0.f;
    }
    if (i == NN - 1) rowstart[NN] = base0 + incl;
}

__global__ __launch_bounds__(256) void k_csr(const int* __restrict__ src, const int* __restrict__ dst,
                                             const int* __restrict__ rowstart, int* __restrict__ cursor,
                                             int* __restrict__ csr_src) {
    int e = blockIdx.x * 256 + threadIdx.x;
    if (e < NE) {
        int d = dst[e];
        int p = atomicAdd(&cursor[d], 1);
        csr_src[rowstart[d] + p] = src[e];
    }
}

// ---------------- AtomEncoder + first conv1 transform ----------------
__global__ __launch_bounds__(256) void k_atom_mm(const int* __restrict__ x, const float* __restrict__ emb,
                                                 const float* __restrict__ W, float* __restrict__ h,
                                                 float* __restrict__ hw) {
    __shared__ float wl[HC * HC];
    __shared__ float il[8][HC];
    int t = threadIdx.x;
    ((float4*)wl)[t] = ((const float4*)W)[t];
    int slot = t >> 5, c = t & 31;
    int n = blockIdx.x * 8 + slot;
    float s = 0.f;
#pragma unroll
    for (int j = 0; j < 9; j++) {
        int v = x[n * 9 + j];
        s += emb[(j * 100 + v) * HC + c];
    }
    __syncthreads();   // staging barrier (weights)
    h[n * HC + c] = s;
    il[slot][c] = s;   // intra-wave sharing only below
    float o = 0.f;
#pragma unroll
    for (int k = 0; k < HC; k++) o += il[slot][k] * wl[k * HC + c];
    hw[n * HC + c] = o;
}

// ---------------- aggregation only: no LDS, no barrier, low VGPR; 512 thr / 16 nodes ----------------
template <int AGGR>
__global__ __launch_bounds__(512) void k_agg(const float* __restrict__ hw,
                                             const int* __restrict__ rowstart, const int* __restrict__ csr_src,
                                             float* __restrict__ aout) {
    int t = threadIdx.x;
    int slot = t >> 5, c = t & 31;
    int sub = c >> 3;
    int ch4 = (c & 7) * 4;
    int n = blockIdx.x * 16 + slot;
    int rs = rowstart[n], re = rowstart[n + 1];
    float4 a4;
    if (AGGR == 0) {
        float4 m4 = make_float4(3.0e38f, 3.0e38f, 3.0e38f, 3.0e38f);
        for (int base = rs; base < re; base += 32) {
            int cnt = min(re - base, 32);
            int myidx = (c < cnt) ? csr_src[base + c] : 0;
#pragma unroll
            for (int jj = 0; jj < 8; jj++) {
                int r = jj * 4 + sub;
                int sidx = __shfl(myidx, r, 32);
                if (r < cnt) {
                    float4 v = *(const float4*)(hw + sidx * HC + ch4);
                    m4.x = fminf(m4.x, v.x); m4.y = fminf(m4.y, v.y);
                    m4.z = fminf(m4.z, v.z); m4.w = fminf(m4.w, v.w);
                }
            }
        }
        float4 o4 = shflx4(m4, 8);
        m4.x = fminf(m4.x, o4.x); m4.y = fminf(m4.y, o4.y); m4.z = fminf(m4.z, o4.z); m4.w = fminf(m4.w, o4.w);
        o4 = shflx4(m4, 16);
        m4.x = fminf(m4.x, o4.x); m4.y = fminf(m4.y, o4.y); m4.z = fminf(m4.z, o4.z); m4.w = fminf(m4.w, o4.w);
        a4 = (re > rs) ? m4 : make_float4(0.f, 0.f, 0.f, 0.f);
    } else {
        float4 lg = make_float4(0.f, 0.f, 0.f, 0.f);
        int4 ng = make_int4(0, 0, 0, 0);
        for (int base = rs; base < re; base += 32) {
            int cnt = min(re - base, 32);
            int myidx = (c < cnt) ? csr_src[base + c] : 0;
#pragma unroll
            for (int jj = 0; jj < 8; jj++) {
                int r = jj * 4 + sub;
                int sidx = __shfl(myidx, r, 32);
                if (r < cnt) {
                    float4 v = *(const float4*)(hw + sidx * HC + ch4);
                    ng.x += (v.x < 0.f) ? 1 : 0; ng.y += (v.y < 0.f) ? 1 : 0;
                    ng.z += (v.z < 0.f) ? 1 : 0; ng.w += (v.w < 0.f) ? 1 : 0;
                    lg.x += __logf(fabsf(v.x)); lg.y += __logf(fabsf(v.y));
                    lg.z += __logf(fabsf(v.z)); lg.w += __logf(fabsf(v.w));
                }
            }
        }
        float4 o4 = shflx4(lg, 8);
        lg.x += o4.x; lg.y += o4.y; lg.z += o4.z; lg.w += o4.w;
        o4 = shflx4(lg, 16);
        lg.x += o4.x; lg.y += o4.y; lg.z += o4.z; lg.w += o4.w;
        ng.x += __shfl_xor(ng.x, 8, 32); ng.y += __shfl_xor(ng.y, 8, 32);
        ng.z += __shfl_xor(ng.z, 8, 32); ng.w += __shfl_xor(ng.w, 8, 32);
        ng.x += __shfl_xor(ng.x, 16, 32); ng.y += __shfl_xor(ng.y, 16, 32);
        ng.z += __shfl_xor(ng.z, 16, 32); ng.w += __shfl_xor(ng.w, 16, 32);
        if (re > rs) {
            float ex = __expf(lg.x); a4.x = (ng.x & 1) ? -ex : ex;
            ex = __expf(lg.y); a4.y = (ng.y & 1) ? -ex : ex;
            ex = __expf(lg.z); a4.z = (ng.z & 1) ? -ex : ex;
            ex = __expf(lg.w); a4.w = (ng.w & 1) ? -ex : ex;
        } else {
            a4 = make_float4(0.f, 0.f, 0.f, 0.f);
        }
    }
    if (c < 8) *(float4*)(aout + n * HC + ch4) = a4;
}

// ---------------- GRU update: node-blocked (4 nodes/thread), b128 LDS, capped unroll ----------------
// 256 threads = 8 slots x 32 channels; block covers 32 nodes. Weights row-contiguous in LDS,
// stride 36 dwords. unroll 1 on k4 loops keeps VGPR < 128 (R10 lesson: full unroll -> 236 VGPR).
// EPI: 0 none, 1 out_next = h@Wn, 2 out_next = relu(h@Wn + nb),
//      3 fused conv3->conv4 handoff: C = relu(h@Wn + nb) in-register, accOut = C@W4, Sout = dinv*C
//        (h state NOT written; accOut may alias h — block-local read-before-write).
#define WS 36   // dword stride for weight rows (9 float4)
template <bool POSTRELU, int EPI>
__global__ __launch_bounds__(256) void k_gru(const float* __restrict__ aIn, float* __restrict__ h,
                                             const float* __restrict__ wih, const float* __restrict__ whh,
                                             const float* __restrict__ bih, const float* __restrict__ bhh,
                                             const float* __restrict__ Wn, const float* __restrict__ nb,
                                             float* __restrict__ out_next,
                                             const float* __restrict__ w4_0, const float* __restrict__ dinvp,
                                             float* __restrict__ accOut, float* __restrict__ Sout) {
    __shared__ float wiL[96 * WS];
    __shared__ float whL[96 * WS];
    __shared__ float wnT[EPI > 0 ? 32 * WS : 4];
    __shared__ float w4T[EPI == 3 ? 32 * WS : 4];
    __shared__ float al[32][HC];
    __shared__ float hl[32][HC];
    int t = threadIdx.x;
    // stage wi/wh row-contiguous (768 float4 each)
    for (int i4 = t; i4 < 768; i4 += 256) {
        int row = i4 >> 3, k4 = i4 & 7;
        ((float4*)wiL)[row * 9 + k4] = ((const float4*)wih)[i4];
        ((float4*)whL)[row * 9 + k4] = ((const float4*)whh)[i4];
    }
    if (EPI > 0) {
        // transpose Wn[k][c] -> wnT[c][k] (stride WS)
        int i = t * 4;
        int k = i >> 5, c0 = i & 31;
        float4 v = ((const float4*)Wn)[t];
        wnT[(c0 + 0) * WS + k] = v.x;
        wnT[(c0 + 1) * WS + k] = v.y;
        wnT[(c0 + 2) * WS + k] = v.z;
        wnT[(c0 + 3) * WS + k] = v.w;
    }
    if (EPI == 3) {
        int i = t * 4;
        int k = i >> 5, c0 = i & 31;
        float4 v = ((const float4*)w4_0)[t];
        w4T[(c0 + 0) * WS + k] = v.x;
        w4T[(c0 + 1) * WS + k] = v.y;
        w4T[(c0 + 2) * WS + k] = v.z;
        w4T[(c0 + 3) * WS + k] = v.w;
    }
    int slot = t >> 5, c = t & 31;
    int nb0 = blockIdx.x * 32 + slot * 4;
    float b_ir = bih[c], b_iz = bih[HC + c], b_in = bih[2 * HC + c];
    float b_hr = bhh[c], b_hz = bhh[HC + c], b_hn = bhh[2 * HC + c];
    float nbv = (EPI >= 2) ? nb[c] : 0.f;
    float hv[4];
#pragma unroll
    for (int j = 0; j < 4; j++) {
        int n = nb0 + j;
        float aa = 0.f, hh = 0.f;
        if (n < NN) {
            aa = aIn[n * HC + c];
            hh = h[n * HC + c];
        }
        hv[j] = hh;
        al[slot * 4 + j][c] = aa;
        hl[slot * 4 + j][c] = hh;
    }
    __syncthreads();   // single barrier: weights staged

    float aIR[4], aIZ[4], aIN[4], aHR[4], aHZ[4], aHN[4];
#pragma unroll
    for (int j = 0; j < 4; j++) {
        aIR[j] = b_ir; aIZ[j] = b_iz; aIN[j] = b_in;
        aHR[j] = b_hr; aHZ[j] = b_hz; aHN[j] = b_hn;
    }
    const float4* wi4 = (const float4*)wiL;
    const float4* wh4 = (const float4*)whL;
    int r0 = c * 9, r1 = (32 + c) * 9, r2 = (64 + c) * 9;
#pragma unroll 1
    for (int k4 = 0; k4 < 8; k4++) {
        float4 wir = wi4[r0 + k4], wiz = wi4[r1 + k4], win = wi4[r2 + k4];
        float4 whr = wh4[r0 + k4], whz = wh4[r1 + k4], whn = wh4[r2 + k4];
#pragma unroll
        for (int j = 0; j < 4; j++) {
            float4 av = *(const float4*)&al[slot * 4 + j][k4 * 4];
            float4 hb = *(const float4*)&hl[slot * 4 + j][k4 * 4];
            aIR[j] += dot4(av, wir);
            aIZ[j] += dot4(av, wiz);
            aIN[j] += dot4(av, win);
            aHR[j] += dot4(hb, whr);
            aHZ[j] += dot4(hb, whz);
            aHN[j] += dot4(hb, whn);
        }
    }
    float hn[4];
#pragma unroll
    for (int j = 0; j < 4; j++) {
        float r = 1.f / (1.f + __expf(-(aIR[j] + aHR[j])));
        float z = 1.f / (1.f + __expf(-(aIZ[j] + aHZ[j])));
        float nnv = tanhf(aIN[j] + r * aHN[j]);
        float v = (1.f - z) * nnv + z * hv[j];
        if (POSTRELU) v = fmaxf(v, 0.f);
        hn[j] = v;
        int n = nb0 + j;
        if (EPI != 3 && n < NN) h[n * HC + c] = v;
    }
    if (EPI == 1 || EPI == 2) {
        // reuse al for h_new (intra-half-wave, lockstep -> no barrier)
#pragma unroll
        for (int j = 0; j < 4; j++) al[slot * 4 + j][c] = hn[j];
        float accE[4];
#pragma unroll
        for (int j = 0; j < 4; j++) accE[j] = (EPI == 2) ? nbv : 0.f;
        const float4* wn4 = (const float4*)wnT;
        int rc = c * 9;
#pragma unroll 1
        for (int k4 = 0; k4 < 8; k4++) {
            float4 wv = wn4[rc + k4];
#pragma unroll
            for (int j = 0; j < 4; j++) {
                float4 hb = *(const float4*)&al[slot * 4 + j][k4 * 4];
                accE[j] += dot4(hb, wv);
            }
        }
#pragma unroll
        for (int j = 0; j < 4; j++) {
            float o = accE[j];
            if (EPI == 2) o = fmaxf(o, 0.f);
            int n = nb0 + j;
            if (n < NN) out_next[n * HC + c] = o;
        }
    } else if (EPI == 3) {
        // C = relu(h_new @ Wn + nb) in-register; acc = C @ w4[0]; S = dinv * C
#pragma unroll
        for (int j = 0; j < 4; j++) al[slot * 4 + j][c] = hn[j];
        float o2[4];
#pragma unroll
        for (int j = 0; j < 4; j++) o2[j] = nbv;
        const float4* wn4 = (const float4*)wnT;
        int rc = c * 9;
#pragma unroll 1
        for (int k4 = 0; k4 < 8; k4++) {
            float4 wv = wn4[rc + k4];
#pragma unroll
            for (int j = 0; j < 4; j++) {
                float4 hb = *(const float4*)&al[slot * 4 + j][k4 * 4];
                o2[j] += dot4(hb, wv);
            }
        }
#pragma unroll
        for (int j = 0; j < 4; j++) {
            o2[j] = fmaxf(o2[j], 0.f);
            hl[slot * 4 + j][c] = o2[j];   // reuse hl, intra-half-wave lockstep
        }
        float accT[4];
#pragma unroll
        for (int j = 0; j < 4; j++) accT[j] = 0.f;
        const float4* w44 = (const float4*)w4T;
#pragma unroll 1
        for (int k4 = 0; k4 < 8; k4++) {
            float4 wv = w44[rc + k4];
#pragma unroll
            for (int j = 0; j < 4; j++) {
                float4 hb = *(const float4*)&hl[slot * 4 + j][k4 * 4];
                accT[j] += dot4(hb, wv);
            }
        }
#pragma unroll
        for (int j = 0; j < 4; j++) {
            int n = nb0 + j;
            if (n < NN) {
                accOut[n * HC + c] = accT[j];
                Sout[n * HC + c] = dinvp[n] * o2[j];
            }
        }
    }
}

// ---------------- conv2: GraphConv sum + two matmuls + ELU ----------------
__global__ __launch_bounds__(256) void k_conv2(const float* __restrict__ h, float* __restrict__ out,
                                               const int* __restrict__ rowstart, const int* __restrict__ csr_src,
                                               const float* __restrict__ rel_w, const float* __restrict__ rel_b,
                                               const float* __restrict__ root_w) {
    __shared__ float rw[HC * HC], ow[HC * HC];
    __shared__ float sl[8][HC], hl[8][HC];
    int t = threadIdx.x;
    ((float4*)rw)[t] = ((const float4*)rel_w)[t];
    ((float4*)ow)[t] = ((const float4*)root_w)[t];
    int slot = t >> 5, c = t & 31;
    int sub = c >> 3;
    int ch4 = (c & 7) * 4;
    int n = blockIdx.x * 8 + slot;
    int rs = rowstart[n], re = rowstart[n + 1];
    __syncthreads();   // staging barrier
    float4 s4 = make_float4(0.f, 0.f, 0.f, 0.f);
    for (int base = rs; base < re; base += 32) {
        int cnt = min(re - base, 32);
        int myidx = (c < cnt) ? csr_src[base + c] : 0;
#pragma unroll
        for (int jj = 0; jj < 8; jj++) {
            int r = jj * 4 + sub;
            int sidx = __shfl(myidx, r, 32);
            if (r < cnt) {
                float4 v = *(const float4*)(h + sidx * HC + ch4);
                s4.x += v.x; s4.y += v.y; s4.z += v.z; s4.w += v.w;
            }
        }
    }
    float4 o4 = shflx4(s4, 8);
    s4.x += o4.x; s4.y += o4.y; s4.z += o4.z; s4.w += o4.w;
    o4 = shflx4(s4, 16);
    s4.x += o4.x; s4.y += o4.y; s4.z += o4.z; s4.w += o4.w;
    if (c < 8) *(float4*)&sl[slot][ch4] = s4;
    float hv = h[n * HC + c];
    hl[slot][c] = hv;
    float o = rel_b[c];
#pragma unroll
    for (int k = 0; k < HC; k++) o += sl[slot][k] * rw[k * HC + c] + hl[slot][k] * ow[k * HC + c];
    o = (o > 0.f) ? o : expm1f(o);
    out[n * HC + c] = o;
}

// ---------------- bn2 reduce (256 blocks -> bounded atomic fan-in) ----------------
__global__ __launch_bounds__(256) void k_bnred(const float* __restrict__ h, float* __restrict__ acc) {
    __shared__ float ls[8][HC], lq[8][HC];
    int t = threadIdx.x, slot = t >> 5, c = t & 31;
    float s = 0.f, q = 0.f;
    for (int n = blockIdx.x * 8 + slot; n < NN; n += gridDim.x * 8) {
        float v = h[n * HC + c];
        s += v;
        q += v * v;
    }
    ls[slot][c] = s;
    lq[slot][c] = q;
    __syncthreads();   // cross-slot reduction: barrier required
    if (slot == 0) {
        for (int i = 1; i < 8; i++) {
            s += ls[i][c];
            q += lq[i][c];
        }
        atomicAdd(&acc[c], s);
        atomicAdd(&acc[HC + c], q);
    }
}

// ---------------- bn2 apply (in place) + first conv3 transform ----------------
__global__ __launch_bounds__(256) void k_bnapply_mm(float* __restrict__ h, const float* __restrict__ acc,
                                                    const float* __restrict__ g_, const float* __restrict__ b,
                                                    const float* __restrict__ W, float* __restrict__ out) {
    __shared__ float wl[HC * HC];
    __shared__ float il[8][HC];
    int t = threadIdx.x;
    ((float4*)wl)[t] = ((const float4*)W)[t];
    int slot = t >> 5, c = t & 31;
    int n = blockIdx.x * 8 + slot;
    float mu = acc[c] * (1.f / NN);
    float var = acc[HC + c] * (1.f / NN) - mu * mu;
    float v = (h[n * HC + c] - mu) * rsqrtf(var + 1e-5f) * g_[c] + b[c];
    __syncthreads();   // staging barrier
    h[n * HC + c] = v;
    il[slot][c] = v;
    float s = 0.f;
#pragma unroll
    for (int k = 0; k < HC; k++) s += il[slot][k] * wl[k * HC + c];
    out[n * HC + c] = s;
}

// ---------------- TAG hop on pre-scaled S; LAST fuses b4 + softplus(lin4) ----------------
template <bool LAST>
__global__ __launch_bounds__(256) void k_tag(const float* __restrict__ S, float* __restrict__ Snew,
                                             float* __restrict__ acc, const float* __restrict__ Wk,
                                             const int* __restrict__ rowstart, const int* __restrict__ csr_src,
                                             const float* __restrict__ dinv,
                                             const float* __restrict__ b4, const float* __restrict__ l4w,
                                             const float* __restrict__ l4b, float* __restrict__ out) {
    __shared__ float wl[HC * HC];
    __shared__ float w2[LAST ? HC * HC : 1];
    __shared__ float cl[8][HC];
    int t = threadIdx.x;
    ((float4*)wl)[t] = ((const float4*)Wk)[t];
    if (LAST) ((float4*)w2)[t] = ((const float4*)l4w)[t];
    int slot = t >> 5, c = t & 31;
    int sub = c >> 3;
    int ch4 = (c & 7) * 4;
    int n = blockIdx.x * 8 + slot;
    int rs = rowstart[n], re = rowstart[n + 1];
    __syncthreads();   // staging barrier
    float4 s4 = make_float4(0.f, 0.f, 0.f, 0.f);
    for (int base = rs; base < re; base += 32) {
        int cnt = min(re - base, 32);
        int myidx = (c < cnt) ? csr_src[base + c] : 0;
#pragma unroll
        for (int jj = 0; jj < 8; jj++) {
            int r = jj * 4 + sub;
            int sidx = __shfl(myidx, r, 32);
            if (r < cnt) {
                float4 v = *(const float4*)(S + sidx * HC + ch4);
                s4.x += v.x; s4.y += v.y; s4.z += v.z; s4.w += v.w;
            }
        }
    }
    float4 o4 = shflx4(s4, 8);
    s4.x += o4.x; s4.y += o4.y; s4.z += o4.z; s4.w += o4.w;
    o4 = shflx4(s4, 16);
    s4.x += o4.x; s4.y += o4.y; s4.z += o4.z; s4.w += o4.w;
    float di = dinv[n];
    if (c < 8) {
        float4 cn4 = make_float4(di * s4.x, di * s4.y, di * s4.z, di * s4.w);
        *(float4*)&cl[slot][ch4] = cn4;
        if (!LAST) {
            float4 sn4 = make_float4(di * cn4.x, di * cn4.y, di * cn4.z, di * cn4.w);
            *(float4*)(Snew + n * HC + ch4) = sn4;
        }
    }
    float o = 0.f;
#pragma unroll
    for (int k = 0; k < HC; k++) o += cl[slot][k] * wl[k * HC + c];
    if (!LAST) {
        acc[n * HC + c] += o;
    } else {
        float tmp = acc[n * HC + c] + o + b4[c];
        cl[slot][c] = tmp;   // intra-wave
        float o2 = l4b[c];
#pragma unroll
        for (int k = 0; k < HC; k++) o2 += cl[slot][k] * w2[k * HC + c];
        out[n * HC + c] = softplusf(o2);
    }
}

// ---------------- conv5: SAGE var-aggr + fused softplus(lin5) ----------------
__global__ __launch_bounds__(256) void k_sage(const float* __restrict__ h, float* __restrict__ out,
                                              const int* __restrict__ rowstart, const int* __restrict__ csr_src,
                                              const float* __restrict__ lw, const float* __restrict__ lb,
                                              const float* __restrict__ rw_, const float* __restrict__ l5w,
                                              const float* __restrict__ l5b) {
    __shared__ float wl[HC * HC], wr[HC * HC], w5[HC * HC];
    __shared__ float vl[8][HC], hl[8][HC];
    int t = threadIdx.x;
    ((float4*)wl)[t] = ((const float4*)lw)[t];
    ((float4*)wr)[t] = ((const float4*)rw_)[t];
    ((float4*)w5)[t] = ((const float4*)l5w)[t];
    int slot = t >> 5, c = t & 31;
    int sub = c >> 3;
    int ch4 = (c & 7) * 4;
    int n = blockIdx.x * 8 + slot;
    int rs = rowstart[n], re = rowstart[n + 1];
    __syncthreads();   // staging barrier
    float4 s4 = make_float4(0.f, 0.f, 0.f, 0.f);
    float4 q4 = make_float4(0.f, 0.f, 0.f, 0.f);
    for (int base = rs; base < re; base += 32) {
        int cnt = min(re - base, 32);
        int myidx = (c < cnt) ? csr_src[base + c] : 0;
#pragma unroll
        for (int jj = 0; jj < 8; jj++) {
            int r = jj * 4 + sub;
            int sidx = __shfl(myidx, r, 32);
            if (r < cnt) {
                float4 v = *(const float4*)(h + sidx * HC + ch4);
                s4.x += v.x; s4.y += v.y; s4.z += v.z; s4.w += v.w;
                q4.x += v.x * v.x; q4.y += v.y * v.y; q4.z += v.z * v.z; q4.w += v.w * v.w;
            }
        }
    }
    float4 o4 = shflx4(s4, 8);
    s4.x += o4.x; s4.y += o4.y; s4.z += o4.z; s4.w += o4.w;
    o4 = shflx4(s4, 16);
    s4.x += o4.x; s4.y += o4.y; s4.z += o4.z; s4.w += o4.w;
    o4 = shflx4(q4, 8);
    q4.x += o4.x; q4.y += o4.y; q4.z += o4.z; q4.w += o4.w;
    o4 = shflx4(q4, 16);
    q4.x += o4.x; q4.y += o4.y; q4.z += o4.z; q4.w += o4.w;
    float dc = fmaxf((float)(re - rs), 1.f);
    float inv = 1.f / dc;
    if (c < 8) {
        float4 var4;
        float m0 = s4.x * inv, m1 = s4.y * inv, m2 = s4.z * inv, m3 = s4.w * inv;
        var4.x = q4.x * inv - m0 * m0;
        var4.y = q4.y * inv - m1 * m1;
        var4.z = q4.z * inv - m2 * m2;
        var4.w = q4.w * inv - m3 * m3;
        *(float4*)&vl[slot][ch4] = var4;
    }
    float hv = h[n * HC + c];
    hl[slot][c] = hv;
    float o = lb[c];
#pragma unroll
    for (int k = 0; k < HC; k++) o += vl[slot][k] * wl[k * HC + c] + hl[slot][k] * wr[k * HC + c];
    vl[slot][c] = o;   // intra-wave
    float o2 = l5b[c];
#pragma unroll
    for (int k = 0; k < HC; k++) o2 += vl[slot][k] * w5[k * HC + c];
    out[n * HC + c] = softplusf(o2);
}

// ---------------- per-graph InstanceNorm + global max pool + final linear ----------------
__global__ __launch_bounds__(256) void k_final(const float* __restrict__ h, const int* __restrict__ batch,
                                               const float* __restrict__ linw, const float* __restrict__ linb,
                                               float* __restrict__ out) {
    __shared__ float r1[8][HC];
    __shared__ float r2[8][HC];
    __shared__ float gmv[HC], grs[HC], pooled[HC];
    int g = blockIdx.x;
    int t = threadIdx.x, slot = t >> 5, c = t & 31;
    int lo = 0, hi = NN;
    while (lo < hi) {
        int mid = (lo + hi) >> 1;
        if (batch[mid] < g) lo = mid + 1;
        else hi = mid;
    }
    int start = lo;
    hi = NN;
    while (lo < hi) {
        int mid = (lo + hi) >> 1;
        if (batch[mid] <= g) lo = mid + 1;
        else hi = mid;
    }
    int end = lo;
    int cnt = end - start;
    float s = 0.f, q = 0.f;
    for (int n = start + slot; n < end; n += 8) {
        float v = h[n * HC + c];
        s += v;
        q += v * v;
    }
    r1[slot][c] = s;
    r2[slot][c] = q;
    __syncthreads();
    if (slot == 0) {
        for (int i = 1; i < 8; i++) {
            s += r1[i][c];
            q += r2[i][c];
        }
        float dc = (cnt > 0) ? (float)cnt : 1.f;
        float m = s / dc;
        float v = fmaxf(q / dc - m * m, 0.f);
        gmv[c] = m;
        grs[c] = rsqrtf(v + 1e-5f);
    }
    __syncthreads();
    float m_ = gmv[c], r_ = grs[c];
    float mx = -3.0e38f;
    for (int n = start + slot; n < end; n += 8) mx = fmaxf(mx, (h[n * HC + c] - m_) * r_);
    r1[slot][c] = mx;
    __syncthreads();
    if (slot == 0) {
        for (int i = 1; i < 8; i++) mx = fmaxf(mx, r1[i][c]);
        pooled[c] = (cnt > 0) ? mx : 0.f;
    }
    __syncthreads();
    if (t < 2) {
        float o = linb[t];
        for (int k = 0; k < HC; k++) o += pooled[k] * linw[k * 2 + t];
        out[g * 2 + t] = o;
    }
}

// ---------------- launch ----------------

static inline size_t alignup(size_t v) { return (v + 255) & ~(size_t)255; }

extern "C" void kernel_launch(void* const* d_in, const int* in_sizes, int n_in,
                              void* d_out, int out_size, void* d_ws, size_t ws_size,
                              hipStream_t stream) {
    const int*   x      = (const int*)d_in[0];
    const int*   ei     = (const int*)d_in[1];
    const int*   batch  = (const int*)d_in[2];
    const float* emb    = (const float*)d_in[3];
    const float* w1     = (const float*)d_in[4];
    const float* g1wih  = (const float*)d_in[5];
    const float* g1whh  = (const float*)d_in[6];
    const float* g1bih  = (const float*)d_in[7];
    const float* g1bhh  = (const float*)d_in[8];
    const float* rel_w  = (const float*)d_in[9];
    const float* rel_b  = (const float*)d_in[10];
    const float* root_w = (const float*)d_in[11];
    const float* bn2g   = (const float*)d_in[12];
    const float* bn2b   = (const float*)d_in[13];
    const float* w3     = (const float*)d_in[14];
    const float* g3wih  = (const float*)d_in[15];
    const float* g3whh  = (const float*)d_in[16];
    const float* g3bih  = (const float*)d_in[17];
    const float* g3bhh  = (const float*)d_in[18];
    const float* lin3w  = (const float*)d_in[19];
    const float* lin3b  = (const float*)d_in[20];
    const float* w4     = (const float*)d_in[21];
    const float* b4     = (const float*)d_in[22];
    const float* lin4w  = (const float*)d_in[23];
    const float* lin4b  = (const float*)d_in[24];
    const float* sagelw = (const float*)d_in[25];
    const float* sagelb = (const float*)d_in[26];
    const float* sagerw = (const float*)d_in[27];
    const float* lin5w  = (const float*)d_in[28];
    const float* lin5b  = (const float*)d_in[29];
    const float* linw   = (const float*)d_in[30];
    const float* linb   = (const float*)d_in[31];

    const int* src = ei;
    const int* dst = ei + NE;

    char* ws = (char*)d_ws;
    size_t off = 0;
    int* deg = (int*)(ws + off); off = alignup(off + (size_t)NN * 4);
    int* cursor = (int*)(ws + off); off = alignup(off + (size_t)NN * 4);
    float* bnacc = (float*)(ws + off); off = alignup(off + 64 * 4);
    size_t zbytes = off;          // deg + cursor + bnacc zeroed
    int* bscan = (int*)(ws + off); off = alignup(off + 256 * 4);
    int* rowstart = (int*)(ws + off); off = alignup(off + (size_t)(NN + 1) * 4);
    float* dinv = (float*)(ws + off); off = alignup(off + (size_t)NN * 4);
    int* csr = (int*)(ws + off); off = alignup(off + (size_t)NE * 4);
    float* A = (float*)(ws + off); off = alignup(off + (size_t)NN * HC * 4);
    float* B = (float*)(ws + off); off = alignup(off + (size_t)NN * HC * 4);
    float* C = (float*)(ws + off); off = alignup(off + (size_t)NN * HC * 4);
    float* D = (float*)(ws + off); off = alignup(off + (size_t)NN * HC * 4);  // aggregated rows

    hipMemsetAsync(ws, 0, zbytes, stream);

    const int ngE = (NE + 255) / 256;
    const int ngN8 = NN / 8;            // 6250
    const int ngN16 = NN / 16;          // 3125 (512-thread k_agg blocks)
    const int ngN32 = (NN + 31) / 32;   // 1563 (gru blocks)

    k_deg<<<ngE, 256, 0, stream>>>(dst, deg);
    k_scan1<<<NSCB, 256, 0, stream>>>(deg, bscan);
    k_scan3<<<NSCB, 256, 0, stream>>>(deg, bscan, rowstart, dinv);
    k_csr<<<ngE, 256, 0, stream>>>(src, dst, rowstart, cursor, csr);

    // AtomEncoder + B = h @ w1[0]; h = A
    k_atom_mm<<<ngN8, 256, 0, stream>>>(x, emb, w1, A, B);

    // conv1: GatedGraphConv(4, min); h = A; transformed feature ping-pongs B/C; D = agg scratch
    k_agg<0><<<ngN16, 512, 0, stream>>>(B, rowstart, csr, D);
    k_gru<false, 1><<<ngN32, 256, 0, stream>>>(D, A, g1wih, g1whh, g1bih, g1bhh, w1 + 1 * HC * HC, nullptr, C,
                                               nullptr, nullptr, nullptr, nullptr);
    k_agg<0><<<ngN16, 512, 0, stream>>>(C, rowstart, csr, D);
    k_gru<false, 1><<<ngN32, 256, 0, stream>>>(D, A, g1wih, g1whh, g1bih, g1bhh, w1 + 2 * HC * HC, nullptr, B,
                                               nullptr, nullptr, nullptr, nullptr);
    k_agg<0><<<ngN16, 512, 0, stream>>>(B, rowstart, csr, D);
    k_gru<false, 1><<<ngN32, 256, 0, stream>>>(D, A, g1wih, g1whh, g1bih, g1bhh, w1 + 3 * HC * HC, nullptr, C,
                                               nullptr, nullptr, nullptr, nullptr);
    k_agg<0><<<ngN16, 512, 0, stream>>>(C, rowstart, csr, D);
    k_gru<true, 0><<<ngN32, 256, 0, stream>>>(D, A, g1wih, g1whh, g1bih, g1bhh, nullptr, nullptr, nullptr,
                                              nullptr, nullptr, nullptr, nullptr);

    // conv2 + elu -> B; bn2 stats (256-block fan-in); bn apply + A = Bn @ w3[0]
    k_conv2<<<ngN8, 256, 0, stream>>>(A, B, rowstart, csr, rel_w, rel_b, root_w);
    k_bnred<<<256, 256, 0, stream>>>(B, bnacc);
    k_bnapply_mm<<<ngN8, 256, 0, stream>>>(B, bnacc, bn2g, bn2b, w3, A);

    // conv3: GatedGraphConv(5, mul); h = B; transformed feature ping-pongs A/C.
    // Last layer uses EPI=3: fuses relu(lin3) + conv4 initial (acc = C@w4[0] -> B, S = dinv*C -> A).
    k_agg<1><<<ngN16, 512, 0, stream>>>(A, rowstart, csr, D);
    k_gru<false, 1><<<ngN32, 256, 0, stream>>>(D, B, g3wih, g3whh, g3bih, g3bhh, w3 + 1 * HC * HC, nullptr, C,
                                               nullptr, nullptr, nullptr, nullptr);
    k_agg<1><<<ngN16, 512, 0, stream>>>(C, rowstart, csr, D);
    k_gru<false, 1><<<ngN32, 256, 0, stream>>>(D, B, g3wih, g3whh, g3bih, g3bhh, w3 + 2 * HC * HC, nullptr, A,
                                               nullptr, nullptr, nullptr, nullptr);
    k_agg<1><<<ngN16, 512, 0, stream>>>(A, rowstart, csr, D);
    k_gru<false, 1><<<ngN32, 256, 0, stream>>>(D, B, g3wih, g3whh, g3bih, g3bhh, w3 + 3 * HC * HC, nullptr, C,
                                               nullptr, nullptr, nullptr, nullptr);
    k_agg<1><<<ngN16, 512, 0, stream>>>(C, rowstart, csr, D);
    k_gru<false, 1><<<ngN32, 256, 0, stream>>>(D, B, g3wih, g3whh, g3bih, g3bhh, w3 + 4 * HC * HC, nullptr, A,
                                               nullptr, nullptr, nullptr, nullptr);
    k_agg<1><<<ngN16, 512, 0, stream>>>(A, rowstart, csr, D);
    k_gru<false, 3><<<ngN32, 256, 0, stream>>>(D, B, g3wih, g3whh, g3bih, g3bhh, lin3w, lin3b, nullptr,
                                               w4, dinv, B /*acc*/, A /*S*/);

    // conv4: TAGConv K=7; acc = B; S ping-pongs A/C; out -> C
    {
        float* Scur = A;
        float* Snxt = C;
        for (int k = 1; k <= 6; k++) {
            k_tag<false><<<ngN8, 256, 0, stream>>>(Scur, Snxt, B, w4 + (size_t)k * HC * HC,
                                                   rowstart, csr, dinv, nullptr, nullptr, nullptr, nullptr);
            float* tmp = Scur; Scur = Snxt; Snxt = tmp;
        }
        k_tag<true><<<ngN8, 256, 0, stream>>>(Scur, nullptr, B, w4 + (size_t)7 * HC * HC,
                                              rowstart, csr, dinv, b4, lin4w, lin4b, C);
    }

    // conv5: SAGE var-aggr + softplus(lin5); h = C -> A
    k_sage<<<ngN8, 256, 0, stream>>>(C, A, rowstart, csr, sagelw, sagelb, sagerw, lin5w, lin5b);

    // bn5 (per-graph InstanceNorm) + max pool + final linear
    k_final<<<NG, 256, 0, stream>>>(A, batch, linw, linb, (float*)d_out);
}